// Round 3
// baseline (789.200 us; speedup 1.0000x reference)
//
#include <hip/hip_runtime.h>
#include <math.h>

constexpr int NN   = 20000;   // nodes
constexpr int EE   = 640000;  // edges
constexpr int RR   = 90;      // relations
constexpr int INF_ = 128;     // in features
constexpr int HID  = 64;      // hidden
constexpr float EPS = 1e-16f;
constexpr int E2   = 646144;  // padded edge capacity: 2524*256, >= EE + 90*63

typedef unsigned short u16;
typedef __attribute__((ext_vector_type(8))) short bf16x8;
typedef __attribute__((ext_vector_type(4))) float f32x4;

__device__ inline u16 f2bf(float f) {
    unsigned int u = __float_as_uint(f);
    unsigned int r = (u + 0x7FFFu + ((u >> 16) & 1u)) >> 16;
    return (u16)r;
}

// order-preserving float<->uint encode (monotone: f<g  <=>  f2ord(f)<f2ord(g))
__device__ inline unsigned f2ord(float f) {
    unsigned u = __float_as_uint(f);
    return (u & 0x80000000u) ? ~u : (u | 0x80000000u);
}
__device__ inline float ord2f(unsigned x) {
    unsigned u = (x & 0x80000000u) ? (x & 0x7FFFFFFFu) : ~x;
    return __uint_as_float(u);
}
// f2ord(-INF) = 0x007FFFFF — table init value
#define ORD_NEGINF 0x007FFFFFu

__global__ void k_fillrec(int4* p, int n) {
    int i = blockIdx.x * blockDim.x + threadIdx.x;
    if (i < n) { int4 r; r.x = 0; r.y = 0; r.z = 0; r.w = -1; p[i] = r; }
}

// ---------------- sort 1: by relation, segment-padded to 64 ----------------
__global__ void k_hist(const int* et, int* hist) {
    __shared__ int lh[RR];
    if (threadIdx.x < RR) lh[threadIdx.x] = 0;
    __syncthreads();
    int i = blockIdx.x * blockDim.x + threadIdx.x;
    if (i < EE) atomicAdd(&lh[et[i]], 1);
    __syncthreads();
    if (threadIdx.x < RR) atomicAdd(&hist[threadIdx.x], lh[threadIdx.x]);
}

__global__ void k_scanPad(const int* hist, int* cursor) {
    if (threadIdx.x == 0) {
        int acc = 0;
        for (int r = 0; r < RR; ++r) {
            cursor[r] = acc;
            acc += (hist[r] + 63) & ~63;   // pad each segment to 64
        }
    }
}

// sortedR records {src, dst, rel, orig}; dummies stay {0,0,0,-1}
// posS[orig] = relation-sorted position (for sorted ae scatter)
__global__ void k_scatter(const int* src, const int* dst, const int* et,
                          int* cursor, int4* sortedR, int* posS) {
    __shared__ int lh[RR];
    __shared__ int lbase[RR];
    if (threadIdx.x < RR) lh[threadIdx.x] = 0;
    __syncthreads();
    int i = blockIdx.x * blockDim.x + threadIdx.x;
    int r = et[i];
    int rank = atomicAdd(&lh[r], 1);
    __syncthreads();
    if (threadIdx.x < RR) {
        int c = lh[threadIdx.x];
        lbase[threadIdx.x] = c ? atomicAdd(&cursor[threadIdx.x], c) : 0;
    }
    __syncthreads();
    int pos = lbase[r] + rank;
    int4 rec; rec.x = src[i]; rec.y = dst[i]; rec.z = r; rec.w = i;
    sortedR[pos] = rec;
    posS[i] = pos;
}

// ---------------- sort 2: by destination ----------------
__global__ void k_histD(const int* dst, int* histD) {
    int i = blockIdx.x * blockDim.x + threadIdx.x;
    if (i < EE) atomicAdd(&histD[dst[i]], 1);
}

__global__ void k_scanD(const int* histD, int* rowptrD, int* cursorD) {
    __shared__ int part[256];
    const int CH = (NN + 255) / 256;
    int tid = threadIdx.x;
    int base = tid * CH;
    int s = 0;
    for (int j = 0; j < CH; ++j) {
        int idx = base + j;
        if (idx < NN) s += histD[idx];
    }
    part[tid] = s;
    __syncthreads();
    if (tid == 0) {
        int acc = 0;
        for (int t = 0; t < 256; ++t) { int v = part[t]; part[t] = acc; acc += v; }
    }
    __syncthreads();
    int acc = part[tid];
    for (int j = 0; j < CH; ++j) {
        int idx = base + j;
        if (idx < NN) {
            rowptrD[idx] = acc;
            cursorD[idx] = acc;
            acc += histD[idx];
        }
    }
    if (tid == 0) rowptrD[NN] = EE;
}

// sortedD records {paddedpos, dst, rel, 0}; posD[paddedpos] = dst-sorted position
__global__ void k_scatterD(const int4* sortedR, int* cursorD, int4* sortedD,
                           int* posD) {
    int i = blockIdx.x * blockDim.x + threadIdx.x;
    if (i >= E2) return;
    int4 rec = sortedR[i];
    if (rec.w < 0) return;
    int pos = atomicAdd(&cursorD[rec.y], 1);
    int4 out; out.x = i; out.y = rec.y; out.z = rec.z; out.w = 0;
    sortedD[pos] = out;
    posD[i] = pos;
}

// ---------------- weight folding ----------------
__global__ void k_w1(const float* att1, const float* basis1, float* w1) {
    int idx = blockIdx.x * blockDim.x + threadIdx.x;
    if (idx >= RR * 2560) return;
    int r = idx / 2560, co = idx - r * 2560;
    float acc = 0.f;
    for (int b = 0; b < 35; ++b) acc += att1[r * 35 + b] * basis1[b * 2560 + co];
    w1[idx] = acc;
}

__global__ void k_wqk1(const float* w1, const float* q1, const float* k1,
                       float* wq1, float* wk1) {
    int idx = blockIdx.x * blockDim.x + threadIdx.x;
    if (idx >= RR * 64 * 4) return;
    int t = idx & 3, c = (idx >> 2) & 63, r = idx >> 8;
    const float* wrow = w1 + (size_t)r * 2560 + c * 40;
    float aq = 0.f, ak = 0.f;
    for (int o = 0; o < 40; ++o) {
        float w = wrow[o];
        aq += w * q1[o * 4 + t];
        ak += w * k1[o * 4 + t];
    }
    wq1[idx] = aq; wk1[idx] = ak;
}

__global__ void k_wqk2(const float* w2, const float* q2, const float* k2,
                       float* wq2, float* wk2) {
    int idx = blockIdx.x * blockDim.x + threadIdx.x;
    if (idx >= RR * 80 * 2) return;
    int t = idx & 1, bc = (idx >> 1) % 80, r = idx / 160;
    int b = bc / 40, c = bc % 40;
    const float* wbase = w2 + (size_t)((r * 2 + b) * 40 + c) * 32;
    float aq = 0.f, ak = 0.f;
    for (int d = 0; d < 32; ++d) {
        float w = wbase[d];
        aq += w * q2[(b * 32 + d) * 2 + t];
        ak += w * k2[(b * 32 + d) * 2 + t];
    }
    wq2[idx] = aq; wk2[idx] = ak;
}

__global__ void k_we(const float* lew, const float* e2, float* we) {
    int idx = threadIdx.x;
    if (idx >= 32) return;
    int i = idx >> 1, t = idx & 1;
    float acc = 0.f;
    for (int j = 0; j < 64; ++j) acc += lew[i * 64 + j] * e2[j * 2 + t];
    we[idx] = acc;
}

// aeS[posS[e]][2] = edge_attr[e] @ we  — coalesced read, scattered 8B write
__global__ __launch_bounds__(256) void k_ae(const float* ea, const float* weg,
                                            const int* posS, float* aeS) {
    __shared__ float wes[32];
    if (threadIdx.x < 32) wes[threadIdx.x] = weg[threadIdx.x];
    __syncthreads();
    int e = blockIdx.x * 256 + threadIdx.x;
    if (e >= EE) return;
    const float4* ep = (const float4*)(ea + (size_t)e * 16);
    float a0 = 0.f, a1 = 0.f;
#pragma unroll
    for (int cc = 0; cc < 4; ++cc) {
        float4 v = ep[cc];
        const float* vv = (const float*)&v;
#pragma unroll
        for (int j = 0; j < 4; ++j) {
            int ii = cc * 4 + j;
            a0 = fmaf(vv[j], wes[ii * 2 + 0], a0);
            a1 = fmaf(vv[j], wes[ii * 2 + 1], a1);
        }
    }
    float2 av; av.x = a0; av.y = a1;
    *(float2*)(aeS + (size_t)posS[e] * 2) = av;
}

// bf16 transposed+padded weights: w1bT[r][o(48)][k(64)]
__global__ void k_w1bT(const float* w1, u16* w1bT) {
    int idx = blockIdx.x * blockDim.x + threadIdx.x;
    if (idx >= RR * 48 * 64) return;
    int k = idx & 63, o = (idx >> 6) % 48, r = idx / (48 * 64);
    float v = (o < 40) ? w1[(size_t)r * 2560 + k * 40 + o] : 0.f;
    w1bT[idx] = f2bf(v);
}

// w2bT[r][b][d(32)][c(64)]  (c padded 40->64 with zeros)
__global__ void k_w2bT(const float* w2, u16* w2bT) {
    int idx = blockIdx.x * blockDim.x + threadIdx.x;
    if (idx >= RR * 2 * 32 * 64) return;
    int c = idx & 63, d = (idx >> 6) & 31, b = (idx >> 11) & 1, r = idx >> 12;
    float v = (c < 40) ? w2[((((size_t)r * 2 + b) * 40) + c) * 32 + d] : 0.f;
    w2bT[idx] = f2bf(v);
}

// h = x @ lin1_w ; also bf16 copy hb
__global__ void k_h(const float* x, const float* lin1_w, float* h, u16* hb) {
    __shared__ float xs[INF_];
    int n = blockIdx.x, t = threadIdx.x;
    xs[t]      = x[(size_t)n * INF_ + t];
    xs[t + 64] = x[(size_t)n * INF_ + t + 64];
    __syncthreads();
    float acc = 0.f;
    for (int i = 0; i < INF_; ++i) acc += xs[i] * lin1_w[i * HID + t];
    h[(size_t)n * HID + t] = acc;
    hb[(size_t)n * HID + t] = f2bf(acc);
}

// ---------------- conv1 attention logits (f32 gathers — precision-critical) --
__device__ __forceinline__ void attn1_compute(const float4* hd4, const float4* hs4,
                                              const float* __restrict__ q,
                                              const float* __restrict__ k,
                                              float* qi, float* kj) {
#pragma unroll
    for (int t = 0; t < 4; ++t) { qi[t] = 0.f; kj[t] = 0.f; }
    for (int cc = 0; cc < 16; ++cc) {
        float4 a = hd4[cc], b = hs4[cc];
        const float* av = (const float*)&a;
        const float* bv = (const float*)&b;
#pragma unroll
        for (int j = 0; j < 4; ++j) {
            const float* q4 = q + (cc * 4 + j) * 4;
            const float* k4 = k + (cc * 4 + j) * 4;
#pragma unroll
            for (int t = 0; t < 4; ++t) {
                qi[t] = fmaf(av[j], q4[t], qi[t]);
                kj[t] = fmaf(bv[j], k4[t], kj[t]);
            }
        }
    }
}

// writes raw logits at dst-sorted position posD[i]
__global__ __launch_bounds__(256) void k_e1s(const int4* sortedR, const float* h,
                                             const float* wq1g, const float* wk1g,
                                             const int* posD, float* alpha1s) {
    __shared__ float qs[256], ks[256];
    int i = blockIdx.x * 256 + threadIdx.x;
    int4 ed = sortedR[i];
    int s = ed.x, d = ed.y, r = ed.z;
    int rFirst = sortedR[(size_t)blockIdx.x * 256].z;
    int rLast  = sortedR[(size_t)blockIdx.x * 256 + 255].z;
    bool allsame = (rFirst == rLast);
    if (allsame) {
        qs[threadIdx.x] = wq1g[(size_t)rFirst * 256 + threadIdx.x];
        ks[threadIdx.x] = wk1g[(size_t)rFirst * 256 + threadIdx.x];
    }
    __syncthreads();
    if (ed.w < 0) return;   // dummy pad edge
    const float4* hd4 = (const float4*)(h + (size_t)d * 64);
    const float4* hs4 = (const float4*)(h + (size_t)s * 64);
    float qi[4], kj[4];
    if (allsame) attn1_compute(hd4, hs4, qs, ks, qi, kj);
    else         attn1_compute(hd4, hs4, wq1g + (size_t)r * 256, wk1g + (size_t)r * 256, qi, kj);
    float4 av;
    av.x = qi[0] * kj[0];
    av.y = qi[1] * kj[1];
    av.z = qi[2] * kj[2];
    av.w = qi[3] * kj[3];
    *(float4*)(alpha1s + (size_t)posD[i] * 4) = av;
}

// ---------------- conv1 transform via MFMA: outj1[i,40] = h[src] @ w1[rel] ---
__global__ __launch_bounds__(256) void k_mfma1(const int4* sortedR, const u16* hb,
                                               const u16* w1bT, float* outj1) {
    int wid = threadIdx.x >> 6, l = threadIdx.x & 63;
    int base = blockIdx.x * 64;
    int r = sortedR[base].z;
    int e0 = base + wid * 16;
    int row16 = l & 15, g = l >> 4;
    bf16x8 a[3][2];
#pragma unroll
    for (int mt = 0; mt < 3; ++mt)
#pragma unroll
        for (int ks = 0; ks < 2; ++ks)
            a[mt][ks] = *(const bf16x8*)(w1bT + ((size_t)r * 48 + mt * 16 + row16) * 64 + ks * 32 + g * 8);
    int s = sortedR[e0 + row16].x;
    bf16x8 b0 = *(const bf16x8*)(hb + (size_t)s * 64 + g * 8);
    bf16x8 b1 = *(const bf16x8*)(hb + (size_t)s * 64 + 32 + g * 8);
    f32x4 acc[3];
#pragma unroll
    for (int mt = 0; mt < 3; ++mt) acc[mt] = (f32x4){0.f, 0.f, 0.f, 0.f};
#pragma unroll
    for (int mt = 0; mt < 3; ++mt) {
        acc[mt] = __builtin_amdgcn_mfma_f32_16x16x32_bf16(a[mt][0], b0, acc[mt], 0, 0, 0);
        acc[mt] = __builtin_amdgcn_mfma_f32_16x16x32_bf16(a[mt][1], b1, acc[mt], 0, 0, 0);
    }
    float* orow = outj1 + (size_t)(e0 + row16) * 40;
#pragma unroll
    for (int mt = 0; mt < 3; ++mt) {
        int col = mt * 16 + g * 4;
        if (col < 40) {
            float4 v; v.x = acc[mt][0]; v.y = acc[mt][1]; v.z = acc[mt][2]; v.w = acc[mt][3];
            *(float4*)(orow + col) = v;
        }
    }
}

// ---------------- conv1 aggregate + wave-local segment softmax ----------------
// alpha1s is dst-ordered (dense, EE entries) -> all alpha reads are linear.
__global__ __launch_bounds__(256) void k_aggr1(const int4* sortedD, const int* rowptrD,
                                               const float* outj1, const float* alpha1s,
                                               const float* wmod, const float* bias1,
                                               float* h1, u16* h1b) {
    __shared__ unsigned smax[4][RR * 4];
    __shared__ float    ssum[4][RR * 4];
    int wid = threadIdx.x >> 6;
    int lane = threadIdx.x & 63;
    int w = blockIdx.x * 4 + wid;       // grid = NN/4 exactly (NN % 4 == 0)
    int beg = rowptrD[w], end = rowptrD[w + 1];
    unsigned* mx = smax[wid];
    float*    sm = ssum[wid];
    // phase A: init table entries for relations present at this dst
    for (int j = beg + lane; j < end; j += 64) {
        int rb = sortedD[j].z * 4;
        mx[rb + 0] = ORD_NEGINF; mx[rb + 1] = ORD_NEGINF;
        mx[rb + 2] = ORD_NEGINF; mx[rb + 3] = ORD_NEGINF;
        sm[rb + 0] = 0.f; sm[rb + 1] = 0.f; sm[rb + 2] = 0.f; sm[rb + 3] = 0.f;
    }
    __syncthreads();
    // phase B: per-(rel,comp) max via LDS ordered-uint atomicMax
    for (int j = beg + lane; j < end; j += 64) {
        float4 a = *(const float4*)(alpha1s + (size_t)j * 4);
        int rb = sortedD[j].z * 4;
        atomicMax(&mx[rb + 0], f2ord(a.x));
        atomicMax(&mx[rb + 1], f2ord(a.y));
        atomicMax(&mx[rb + 2], f2ord(a.z));
        atomicMax(&mx[rb + 3], f2ord(a.w));
    }
    __syncthreads();
    // phase C: per-(rel,comp) sum of exp via LDS float atomicAdd
    for (int j = beg + lane; j < end; j += 64) {
        float4 a = *(const float4*)(alpha1s + (size_t)j * 4);
        int rb = sortedD[j].z * 4;
        atomicAdd(&sm[rb + 0], __expf(a.x - ord2f(mx[rb + 0])));
        atomicAdd(&sm[rb + 1], __expf(a.y - ord2f(mx[rb + 1])));
        atomicAdd(&sm[rb + 2], __expf(a.z - ord2f(mx[rb + 2])));
        atomicAdd(&sm[rb + 3], __expf(a.w - ord2f(mx[rb + 3])));
    }
    __syncthreads();
    // phase C2: sums -> reciprocals (touches stale entries harmlessly)
    for (int t = lane; t < RR * 4; t += 64) sm[t] = 1.f / (sm[t] + EPS);
    __syncthreads();
    // phase D: aggregate (channel-parallel, recompute exp per edge)
    int hh = lane >= 20 ? 1 : 0;
    int oo = lane - hh * 20;
    float acc0 = 0.f, acc1 = 0.f, accw = 0.f;
    if (lane < 40) {
        for (int j = beg; j < end; ++j) {
            int4 rec = sortedD[j];
            int i = rec.x, rb = rec.z * 4 + hh * 2;
            float v = outj1[(size_t)i * 40 + lane];
            float2 a = *(const float2*)(alpha1s + (size_t)j * 4 + hh * 2);
            float e0 = __expf(a.x - ord2f(mx[rb]));
            float e1 = __expf(a.y - ord2f(mx[rb + 1]));
            acc0 = fmaf(v, e0 * sm[rb], acc0);
            acc1 = fmaf(v, e1 * sm[rb + 1], acc1);
            accw += v;
        }
        float wm = wmod[oo];
        int b0 = hh * 40 + oo;
        float o0 = fmaxf(acc0 + wm * accw + bias1[b0], 0.f);
        float o1 = fmaxf(acc1 + wm * accw + bias1[b0 + 20], 0.f);
        h1[(size_t)w * 80 + b0]      = o0;
        h1[(size_t)w * 80 + b0 + 20] = o1;
        // h1b[n][b(2)][c(64)]: b=hh, c=oo and oo+20 (MFMA layout, zero-padded)
        h1b[((size_t)w * 2 + hh) * 64 + oo]      = f2bf(o0);
        h1b[((size_t)w * 2 + hh) * 64 + oo + 20] = f2bf(o1);
    } else {
        int lam = lane - 40;   // 0..23 -> zero pads c=40..63 for both b
        h1b[((size_t)w * 2 + 0) * 64 + 40 + lam] = 0;
        h1b[((size_t)w * 2 + 1) * 64 + 40 + lam] = 0;
    }
}

// ---------------- conv2 attention logits (f32 gathers) ----------------
__device__ __forceinline__ void attn2_compute(const float4* hd4, const float4* hs4,
                                              const float* __restrict__ q,
                                              const float* __restrict__ k,
                                              float* a) {
    a[0] = 0.f; a[1] = 0.f;
    for (int cc = 0; cc < 20; ++cc) {
        float4 x = hd4[cc], y = hs4[cc];
        const float* xv = (const float*)&x;
        const float* yv = (const float*)&y;
#pragma unroll
        for (int j = 0; j < 4; ++j) {
            int bc = cc * 4 + j;
            a[0] = fmaf(xv[j], q[bc * 2 + 0], fmaf(yv[j], k[bc * 2 + 0], a[0]));
            a[1] = fmaf(xv[j], q[bc * 2 + 1], fmaf(yv[j], k[bc * 2 + 1], a[1]));
        }
    }
}

// writes raw leaky-relu logits at dst-sorted position posD[i]
__global__ __launch_bounds__(256) void k_f1s(const int4* sortedR, const float* h1,
                                             const float* wq2g, const float* wk2g,
                                             const float* aeS, const int* posD,
                                             float* alpha2s) {
    __shared__ float qs[160], ks[160];
    int i = blockIdx.x * 256 + threadIdx.x;
    int4 ed = sortedR[i];
    int s = ed.x, d = ed.y, r = ed.z, e = ed.w;
    int rFirst = sortedR[(size_t)blockIdx.x * 256].z;
    int rLast  = sortedR[(size_t)blockIdx.x * 256 + 255].z;
    bool allsame = (rFirst == rLast);
    if (allsame && threadIdx.x < 160) {
        qs[threadIdx.x] = wq2g[(size_t)rFirst * 160 + threadIdx.x];
        ks[threadIdx.x] = wk2g[(size_t)rFirst * 160 + threadIdx.x];
    }
    __syncthreads();
    if (e < 0) return;   // dummy pad edge
    const float4* hd4 = (const float4*)(h1 + (size_t)d * 80);
    const float4* hs4 = (const float4*)(h1 + (size_t)s * 80);
    float a[2];
    if (allsame) attn2_compute(hd4, hs4, qs, ks, a);
    else         attn2_compute(hd4, hs4, wq2g + (size_t)r * 160, wk2g + (size_t)r * 160, a);
    float2 aev = *(const float2*)(aeS + (size_t)i * 2);   // linear (sorted order)
    a[0] += aev.x;
    a[1] += aev.y;
    a[0] = a[0] > 0.f ? a[0] : 0.2f * a[0];
    a[1] = a[1] > 0.f ? a[1] : 0.2f * a[1];
    float2 av; av.x = a[0]; av.y = a[1];
    *(float2*)(alpha2s + (size_t)posD[i] * 2) = av;
}

// ---------------- conv2 transform via MFMA (block-diagonal, K padded 40->64) -
__global__ __launch_bounds__(256) void k_mfma2(const int4* sortedR, const u16* h1b,
                                               const u16* w2bT, float* outj2) {
    int wid = threadIdx.x >> 6, l = threadIdx.x & 63;
    int base = blockIdx.x * 64;
    int r = sortedR[base].z;
    int e0 = base + wid * 16;
    int row16 = l & 15, g = l >> 4;
    bf16x8 a[2][2][2];   // [b][mt][ks]
#pragma unroll
    for (int b = 0; b < 2; ++b)
#pragma unroll
        for (int mt = 0; mt < 2; ++mt)
#pragma unroll
            for (int ks = 0; ks < 2; ++ks)
                a[b][mt][ks] = *(const bf16x8*)(w2bT + ((((size_t)r * 2 + b) * 32) + mt * 16 + row16) * 64 + ks * 32 + g * 8);
    int s = sortedR[e0 + row16].x;
    bf16x8 bb[2][2];
#pragma unroll
    for (int b = 0; b < 2; ++b)
#pragma unroll
        for (int ks = 0; ks < 2; ++ks)
            bb[b][ks] = *(const bf16x8*)(h1b + ((size_t)s * 2 + b) * 64 + ks * 32 + g * 8);
    f32x4 acc[2][2];
#pragma unroll
    for (int b = 0; b < 2; ++b)
#pragma unroll
        for (int mt = 0; mt < 2; ++mt) acc[b][mt] = (f32x4){0.f, 0.f, 0.f, 0.f};
#pragma unroll
    for (int b = 0; b < 2; ++b)
#pragma unroll
        for (int mt = 0; mt < 2; ++mt) {
            acc[b][mt] = __builtin_amdgcn_mfma_f32_16x16x32_bf16(a[b][mt][0], bb[b][0], acc[b][mt], 0, 0, 0);
            acc[b][mt] = __builtin_amdgcn_mfma_f32_16x16x32_bf16(a[b][mt][1], bb[b][1], acc[b][mt], 0, 0, 0);
        }
    float* orow = outj2 + (size_t)(e0 + row16) * 64;
#pragma unroll
    for (int b = 0; b < 2; ++b)
#pragma unroll
        for (int mt = 0; mt < 2; ++mt) {
            float4 v; v.x = acc[b][mt][0]; v.y = acc[b][mt][1]; v.z = acc[b][mt][2]; v.w = acc[b][mt][3];
            *(float4*)(orow + b * 32 + mt * 16 + g * 4) = v;
        }
}

// ---------------- conv2 aggregate + wave-local softmax (per-dst segments) ----
// alpha2s is dst-ordered -> linear reads.
__global__ __launch_bounds__(256) void k_aggr2(const int4* sortedD, const int* rowptrD,
                                               const float* outj2, const float* alpha2s,
                                               float* h2) {
    int w = blockIdx.x * 4 + (threadIdx.x >> 6);
    int lane = threadIdx.x & 63;
    if (w >= NN) return;
    int beg = rowptrD[w], end = rowptrD[w + 1];
    // phase B: per-dst max (2 comps) via lane-partial + shuffle reduce
    float m0 = -INFINITY, m1 = -INFINITY;
    for (int j = beg + lane; j < end; j += 64) {
        float2 a = *(const float2*)(alpha2s + (size_t)j * 2);
        m0 = fmaxf(m0, a.x); m1 = fmaxf(m1, a.y);
    }
#pragma unroll
    for (int off = 32; off; off >>= 1) {
        m0 = fmaxf(m0, __shfl_xor(m0, off));
        m1 = fmaxf(m1, __shfl_xor(m1, off));
    }
    // phase C: sum of exp
    float s0 = 0.f, s1 = 0.f;
    for (int j = beg + lane; j < end; j += 64) {
        float2 a = *(const float2*)(alpha2s + (size_t)j * 2);
        s0 += __expf(a.x - m0); s1 += __expf(a.y - m1);
    }
#pragma unroll
    for (int off = 32; off; off >>= 1) {
        s0 += __shfl_xor(s0, off);
        s1 += __shfl_xor(s1, off);
    }
    // phase D: aggregate (channel-parallel, recompute exp per edge)
    int b = lane >> 5;
    float mb = b ? m1 : m0;
    float rs = 1.f / ((b ? s1 : s0) + EPS);
    float acc = 0.f;
    for (int j = beg; j < end; ++j) {
        int i = sortedD[j].x;
        float v = outj2[(size_t)i * 64 + lane];
        float a = alpha2s[(size_t)j * 2 + b];
        acc = fmaf(v, __expf(a - mb) * rs, acc);
    }
    h2[(size_t)w * 64 + lane] = acc;
}

__global__ void k_out(const float* h2, const float* lin2_w, const float* lin2_b,
                      float* out) {
    int n = blockIdx.x * blockDim.x + threadIdx.x;
    if (n >= NN) return;
    float o[4] = {lin2_b[0], lin2_b[1], lin2_b[2], lin2_b[3]};
    const float* hr = h2 + (size_t)n * 64;
    for (int c = 0; c < 64; ++c) {
        float hv = hr[c];
#pragma unroll
        for (int t = 0; t < 4; ++t) o[t] = fmaf(hv, lin2_w[c * 4 + t], o[t]);
    }
    float m = fmaxf(fmaxf(o[0], o[1]), fmaxf(o[2], o[3]));
    float s = __expf(o[0] - m) + __expf(o[1] - m) + __expf(o[2] - m) + __expf(o[3] - m);
    float lse = m + logf(s);
#pragma unroll
    for (int t = 0; t < 4; ++t) out[(size_t)n * 4 + t] = o[t] - lse;
}

extern "C" void kernel_launch(void* const* d_in, const int* in_sizes, int n_in,
                              void* d_out, int out_size, void* d_ws, size_t ws_size,
                              hipStream_t stream) {
    const float* x        = (const float*)d_in[0];
    const int*   eidx     = (const int*)d_in[1];
    const int*   etype    = (const int*)d_in[2];
    const float* eattr    = (const float*)d_in[3];
    const float* lin1_w   = (const float*)d_in[4];
    const float* att1     = (const float*)d_in[5];
    const float* basis1   = (const float*)d_in[6];
    const float* q1       = (const float*)d_in[7];
    const float* k1       = (const float*)d_in[8];
    const float* wmod1    = (const float*)d_in[9];
    const float* bias1    = (const float*)d_in[10];
    const float* w2       = (const float*)d_in[11];
    const float* q2       = (const float*)d_in[12];
    const float* k2       = (const float*)d_in[13];
    const float* lew      = (const float*)d_in[14];
    const float* e2i      = (const float*)d_in[15];
    const float* lin2_w   = (const float*)d_in[16];
    const float* lin2_b   = (const float*)d_in[17];

    const int* src = eidx;
    const int* dst = eidx + EE;

    // ---------------- workspace layout (f32 units) ----------------
    float* W = (float*)d_ws;
    float* w1      = W;   W += 230400;
    float* wq1     = W;   W += 23040;
    float* wk1     = W;   W += 23040;
    float* wq2     = W;   W += 14400;
    float* wk2     = W;   W += 14400;
    float* we      = W;   W += 32;
    float* h       = W;   W += (size_t)NN * 64;
    float* h1      = W;   W += (size_t)NN * 80;
    float* h2      = W;   W += (size_t)NN * 64;
    float* aeS     = W;   W += (size_t)E2 * 2;
    u16*   hb      = (u16*)W;   W += (size_t)NN * 64 / 2;        // N*64 bf16
    u16*   h1b     = (u16*)W;   W += (size_t)NN * 128 / 2;       // N*2*64 bf16 (MFMA)
    u16*   w1bT    = (u16*)W;   W += (size_t)RR * 48 * 64 / 2;
    u16*   w2bT    = (u16*)W;   W += (size_t)RR * 2 * 32 * 64 / 2;
    // union: conv1 {outj1[E2*40], alpha1s[EE*4]} / conv2 {outj2[E2*64]}
    // (outj2 overlaps alpha1s but is written only after k_aggr1 completes)
    float* uni     = W;   W += (size_t)E2 * 64;
    float* outj1   = uni;
    float* alpha1s = uni + (size_t)E2 * 40;
    float* outj2   = uni;
    float* alpha2s = W;   W += (size_t)EE * 2;
    int4*  sortedR = (int4*)W;
    int*   I = (int*)W;   I += (size_t)E2 * 4;
    int4*  sortedD = (int4*)I;  I += (size_t)E2 * 4;
    int*   posS    = I;   I += EE;
    int*   posD    = I;   I += E2;
    int*   rowptrD = I;   I += NN + 1;
    int*   cursorD = I;   I += NN;
    int*   histD   = I;   I += NN;    // zeroed block starts here
    int*   hist    = I;   I += 128;
    int*   cursor  = I;   I += 128;

    // ---------------- init ----------------
    hipMemsetAsync(histD, 0, (size_t)(NN + 256) * 4, stream);
    k_fillrec<<<E2 / 256, 256, 0, stream>>>(sortedR, E2);

    // sorts
    k_hist<<<EE / 256, 256, 0, stream>>>(etype, hist);
    k_scanPad<<<1, 64, 0, stream>>>(hist, cursor);
    k_scatter<<<EE / 256, 256, 0, stream>>>(src, dst, etype, cursor, sortedR, posS);
    k_histD<<<EE / 256, 256, 0, stream>>>(dst, histD);
    k_scanD<<<1, 256, 0, stream>>>(histD, rowptrD, cursorD);
    k_scatterD<<<E2 / 256, 256, 0, stream>>>(sortedR, cursorD, sortedD, posD);

    // folded weights + bf16 prep + dense input layer + edge-attr logits
    k_w1<<<(RR * 2560 + 255) / 256, 256, 0, stream>>>(att1, basis1, w1);
    k_wqk1<<<(RR * 256 + 255) / 256, 256, 0, stream>>>(w1, q1, k1, wq1, wk1);
    k_wqk2<<<(RR * 160 + 255) / 256, 256, 0, stream>>>(w2, q2, k2, wq2, wk2);
    k_we<<<1, 32, 0, stream>>>(lew, e2i, we);
    k_ae<<<EE / 256, 256, 0, stream>>>(eattr, we, posS, aeS);
    k_w1bT<<<(RR * 48 * 64) / 256, 256, 0, stream>>>(w1, w1bT);
    k_w2bT<<<(RR * 2 * 32 * 64) / 256, 256, 0, stream>>>(w2, w2bT);
    k_h<<<NN, 64, 0, stream>>>(x, lin1_w, h, hb);

    // conv1
    k_e1s<<<E2 / 256, 256, 0, stream>>>(sortedR, h, wq1, wk1, posD, alpha1s);
    k_mfma1<<<E2 / 64, 256, 0, stream>>>(sortedR, hb, w1bT, outj1);
    k_aggr1<<<NN / 4, 256, 0, stream>>>(sortedD, rowptrD, outj1, alpha1s,
                                        wmod1, bias1, h1, h1b);

    // conv2 (outj2 aliases dead conv1 buffers)
    k_f1s<<<E2 / 256, 256, 0, stream>>>(sortedR, h1, wq2, wk2, aeS, posD, alpha2s);
    k_mfma2<<<E2 / 64, 256, 0, stream>>>(sortedR, h1b, w2bT, outj2);
    k_aggr2<<<(NN + 3) / 4, 256, 0, stream>>>(sortedD, rowptrD, outj2, alpha2s, h2);

    k_out<<<(NN + 255) / 256, 256, 0, stream>>>(h2, lin2_w, lin2_b, (float*)d_out);
}

// Round 4
// 699.277 us; speedup vs baseline: 1.1286x; 1.1286x over previous
//
#include <hip/hip_runtime.h>
#include <math.h>

constexpr int NN   = 20000;   // nodes
constexpr int EE   = 640000;  // edges
constexpr int RR   = 90;      // relations
constexpr int INF_ = 128;     // in features
constexpr int HID  = 64;      // hidden
constexpr float EPS = 1e-16f;
constexpr int E2   = 646144;  // padded edge capacity: 2524*256, >= EE + 90*63

typedef unsigned short u16;
typedef _Float16 f16;
typedef __attribute__((ext_vector_type(8))) short bf16x8;
typedef __attribute__((ext_vector_type(8))) _Float16 f16x8;
typedef __attribute__((ext_vector_type(4))) float f32x4;

__device__ inline u16 f2bf(float f) {
    unsigned int u = __float_as_uint(f);
    unsigned int r = (u + 0x7FFFu + ((u >> 16) & 1u)) >> 16;
    return (u16)r;
}

// order-preserving float<->uint encode (monotone: f<g  <=>  f2ord(f)<f2ord(g))
__device__ inline unsigned f2ord(float f) {
    unsigned u = __float_as_uint(f);
    return (u & 0x80000000u) ? ~u : (u | 0x80000000u);
}
__device__ inline float ord2f(unsigned x) {
    unsigned u = (x & 0x80000000u) ? (x & 0x7FFFFFFFu) : ~x;
    return __uint_as_float(u);
}
// f2ord(-INF) = 0x007FFFFF — table init value
#define ORD_NEGINF 0x007FFFFFu

__global__ void k_fillrec(int4* p, int n) {
    int i = blockIdx.x * blockDim.x + threadIdx.x;
    if (i < n) { int4 r; r.x = 0; r.y = 0; r.z = 0; r.w = -1; p[i] = r; }
}

// ---------------- sort 1: by relation, segment-padded to 64 ----------------
__global__ void k_hist(const int* et, int* hist) {
    __shared__ int lh[RR];
    if (threadIdx.x < RR) lh[threadIdx.x] = 0;
    __syncthreads();
    int i = blockIdx.x * blockDim.x + threadIdx.x;
    if (i < EE) atomicAdd(&lh[et[i]], 1);
    __syncthreads();
    if (threadIdx.x < RR) atomicAdd(&hist[threadIdx.x], lh[threadIdx.x]);
}

__global__ void k_scanPad(const int* hist, int* cursor) {
    if (threadIdx.x == 0) {
        int acc = 0;
        for (int r = 0; r < RR; ++r) {
            cursor[r] = acc;
            acc += (hist[r] + 63) & ~63;   // pad each segment to 64
        }
    }
}

// sortedR records {src, dst, rel, orig}; dummies stay {0,0,0,-1}
// posS[orig] = relation-sorted position (for sorted ae scatter)
__global__ void k_scatter(const int* src, const int* dst, const int* et,
                          int* cursor, int4* sortedR, int* posS) {
    __shared__ int lh[RR];
    __shared__ int lbase[RR];
    if (threadIdx.x < RR) lh[threadIdx.x] = 0;
    __syncthreads();
    int i = blockIdx.x * blockDim.x + threadIdx.x;
    int r = et[i];
    int rank = atomicAdd(&lh[r], 1);
    __syncthreads();
    if (threadIdx.x < RR) {
        int c = lh[threadIdx.x];
        lbase[threadIdx.x] = c ? atomicAdd(&cursor[threadIdx.x], c) : 0;
    }
    __syncthreads();
    int pos = lbase[r] + rank;
    int4 rec; rec.x = src[i]; rec.y = dst[i]; rec.z = r; rec.w = i;
    sortedR[pos] = rec;
    posS[i] = pos;
}

// ---------------- sort 2: by destination ----------------
__global__ void k_histD(const int* dst, int* histD) {
    int i = blockIdx.x * blockDim.x + threadIdx.x;
    if (i < EE) atomicAdd(&histD[dst[i]], 1);
}

__global__ void k_scanD(const int* histD, int* rowptrD, int* cursorD) {
    __shared__ int part[256];
    const int CH = (NN + 255) / 256;
    int tid = threadIdx.x;
    int base = tid * CH;
    int s = 0;
    for (int j = 0; j < CH; ++j) {
        int idx = base + j;
        if (idx < NN) s += histD[idx];
    }
    part[tid] = s;
    __syncthreads();
    if (tid == 0) {
        int acc = 0;
        for (int t = 0; t < 256; ++t) { int v = part[t]; part[t] = acc; acc += v; }
    }
    __syncthreads();
    int acc = part[tid];
    for (int j = 0; j < CH; ++j) {
        int idx = base + j;
        if (idx < NN) {
            rowptrD[idx] = acc;
            cursorD[idx] = acc;
            acc += histD[idx];
        }
    }
    if (tid == 0) rowptrD[NN] = EE;
}

// sortedD records {paddedpos, dst, rel, 0}; posD[paddedpos] = dst-sorted position
__global__ void k_scatterD(const int4* sortedR, int* cursorD, int4* sortedD,
                           int* posD) {
    int i = blockIdx.x * blockDim.x + threadIdx.x;
    if (i >= E2) return;
    int4 rec = sortedR[i];
    if (rec.w < 0) return;
    int pos = atomicAdd(&cursorD[rec.y], 1);
    int4 out; out.x = i; out.y = rec.y; out.z = rec.z; out.w = 0;
    sortedD[pos] = out;
    posD[i] = pos;
}

// ---------------- weight folding ----------------
__global__ void k_w1(const float* att1, const float* basis1, float* w1) {
    int idx = blockIdx.x * blockDim.x + threadIdx.x;
    if (idx >= RR * 2560) return;
    int r = idx / 2560, co = idx - r * 2560;
    float acc = 0.f;
    for (int b = 0; b < 35; ++b) acc += att1[r * 35 + b] * basis1[b * 2560 + co];
    w1[idx] = acc;
}

__global__ void k_wqk1(const float* w1, const float* q1, const float* k1,
                       float* wq1, float* wk1) {
    int idx = blockIdx.x * blockDim.x + threadIdx.x;
    if (idx >= RR * 64 * 4) return;
    int t = idx & 3, c = (idx >> 2) & 63, r = idx >> 8;
    const float* wrow = w1 + (size_t)r * 2560 + c * 40;
    float aq = 0.f, ak = 0.f;
    for (int o = 0; o < 40; ++o) {
        float w = wrow[o];
        aq += w * q1[o * 4 + t];
        ak += w * k1[o * 4 + t];
    }
    wq1[idx] = aq; wk1[idx] = ak;
}

__global__ void k_wqk2(const float* w2, const float* q2, const float* k2,
                       float* wq2, float* wk2) {
    int idx = blockIdx.x * blockDim.x + threadIdx.x;
    if (idx >= RR * 80 * 2) return;
    int t = idx & 1, bc = (idx >> 1) % 80, r = idx / 160;
    int b = bc / 40, c = bc % 40;
    const float* wbase = w2 + (size_t)((r * 2 + b) * 40 + c) * 32;
    float aq = 0.f, ak = 0.f;
    for (int d = 0; d < 32; ++d) {
        float w = wbase[d];
        aq += w * q2[(b * 32 + d) * 2 + t];
        ak += w * k2[(b * 32 + d) * 2 + t];
    }
    wq2[idx] = aq; wk2[idx] = ak;
}

__global__ void k_we(const float* lew, const float* e2, float* we) {
    int idx = threadIdx.x;
    if (idx >= 32) return;
    int i = idx >> 1, t = idx & 1;
    float acc = 0.f;
    for (int j = 0; j < 64; ++j) acc += lew[i * 64 + j] * e2[j * 2 + t];
    we[idx] = acc;
}

// aeS[posS[e]][2] = edge_attr[e] @ we  — coalesced read, scattered 8B write
__global__ __launch_bounds__(256) void k_ae(const float* ea, const float* weg,
                                            const int* posS, float* aeS) {
    __shared__ float wes[32];
    if (threadIdx.x < 32) wes[threadIdx.x] = weg[threadIdx.x];
    __syncthreads();
    int e = blockIdx.x * 256 + threadIdx.x;
    if (e >= EE) return;
    const float4* ep = (const float4*)(ea + (size_t)e * 16);
    float a0 = 0.f, a1 = 0.f;
#pragma unroll
    for (int cc = 0; cc < 4; ++cc) {
        float4 v = ep[cc];
        const float* vv = (const float*)&v;
#pragma unroll
        for (int j = 0; j < 4; ++j) {
            int ii = cc * 4 + j;
            a0 = fmaf(vv[j], wes[ii * 2 + 0], a0);
            a1 = fmaf(vv[j], wes[ii * 2 + 1], a1);
        }
    }
    float2 av; av.x = a0; av.y = a1;
    *(float2*)(aeS + (size_t)posS[e] * 2) = av;
}

// bf16 transposed+padded weights: w1bT[r][o(48)][k(64)]
__global__ void k_w1bT(const float* w1, u16* w1bT) {
    int idx = blockIdx.x * blockDim.x + threadIdx.x;
    if (idx >= RR * 48 * 64) return;
    int k = idx & 63, o = (idx >> 6) % 48, r = idx / (48 * 64);
    float v = (o < 40) ? w1[(size_t)r * 2560 + k * 40 + o] : 0.f;
    w1bT[idx] = f2bf(v);
}

// w2bT[r][b][d(32)][c(64)]  (c padded 40->64 with zeros)
__global__ void k_w2bT(const float* w2, u16* w2bT) {
    int idx = blockIdx.x * blockDim.x + threadIdx.x;
    if (idx >= RR * 2 * 32 * 64) return;
    int c = idx & 63, d = (idx >> 6) & 31, b = (idx >> 11) & 1, r = idx >> 12;
    float v = (c < 40) ? w2[((((size_t)r * 2 + b) * 40) + c) * 32 + d] : 0.f;
    w2bT[idx] = f2bf(v);
}

// hh = f16(x @ lin1_w) for logit gathers ; hb = bf16 copy for MFMA
__global__ void k_h(const float* x, const float* lin1_w, f16* hh, u16* hb) {
    __shared__ float xs[INF_];
    int n = blockIdx.x, t = threadIdx.x;
    xs[t]      = x[(size_t)n * INF_ + t];
    xs[t + 64] = x[(size_t)n * INF_ + t + 64];
    __syncthreads();
    float acc = 0.f;
    for (int i = 0; i < INF_; ++i) acc += xs[i] * lin1_w[i * HID + t];
    hh[(size_t)n * HID + t] = (f16)acc;
    hb[(size_t)n * HID + t] = f2bf(acc);
}

// ---------------- conv1 attention logits (f16 gathers, f32 math) ----------
__device__ __forceinline__ void attn1_compute(const f16x8* hd, const f16x8* hs,
                                              const float* __restrict__ q,
                                              const float* __restrict__ k,
                                              float* qi, float* kj) {
#pragma unroll
    for (int t = 0; t < 4; ++t) { qi[t] = 0.f; kj[t] = 0.f; }
#pragma unroll
    for (int cc = 0; cc < 8; ++cc) {       // 8 x f16x8 = 64 elems
        f16x8 a = hd[cc], b = hs[cc];
#pragma unroll
        for (int j = 0; j < 8; ++j) {
            float av = (float)a[j];
            float bv = (float)b[j];
            const float* q4 = q + (cc * 8 + j) * 4;
            const float* k4 = k + (cc * 8 + j) * 4;
#pragma unroll
            for (int t = 0; t < 4; ++t) {
                qi[t] = fmaf(av, q4[t], qi[t]);
                kj[t] = fmaf(bv, k4[t], kj[t]);
            }
        }
    }
}

// writes raw logits at dst-sorted position posD[i]
__global__ __launch_bounds__(256) void k_e1s(const int4* sortedR, const f16* hh,
                                             const float* wq1g, const float* wk1g,
                                             const int* posD, float* alpha1s) {
    __shared__ float qs[256], ks[256];
    int i = blockIdx.x * 256 + threadIdx.x;
    int4 ed = sortedR[i];
    int s = ed.x, d = ed.y, r = ed.z;
    int rFirst = sortedR[(size_t)blockIdx.x * 256].z;
    int rLast  = sortedR[(size_t)blockIdx.x * 256 + 255].z;
    bool allsame = (rFirst == rLast);
    if (allsame) {
        qs[threadIdx.x] = wq1g[(size_t)rFirst * 256 + threadIdx.x];
        ks[threadIdx.x] = wk1g[(size_t)rFirst * 256 + threadIdx.x];
    }
    __syncthreads();
    if (ed.w < 0) return;   // dummy pad edge
    const f16x8* hd = (const f16x8*)(hh + (size_t)d * 64);
    const f16x8* hs = (const f16x8*)(hh + (size_t)s * 64);
    float qi[4], kj[4];
    if (allsame) attn1_compute(hd, hs, qs, ks, qi, kj);
    else         attn1_compute(hd, hs, wq1g + (size_t)r * 256, wk1g + (size_t)r * 256, qi, kj);
    float4 av;
    av.x = qi[0] * kj[0];
    av.y = qi[1] * kj[1];
    av.z = qi[2] * kj[2];
    av.w = qi[3] * kj[3];
    *(float4*)(alpha1s + (size_t)posD[i] * 4) = av;
}

// ---------------- conv1 transform via MFMA: outj1[i,40] = h[src] @ w1[rel] ---
__global__ __launch_bounds__(256) void k_mfma1(const int4* sortedR, const u16* hb,
                                               const u16* w1bT, float* outj1) {
    int wid = threadIdx.x >> 6, l = threadIdx.x & 63;
    int base = blockIdx.x * 64;
    int r = sortedR[base].z;
    int e0 = base + wid * 16;
    int row16 = l & 15, g = l >> 4;
    bf16x8 a[3][2];
#pragma unroll
    for (int mt = 0; mt < 3; ++mt)
#pragma unroll
        for (int ks = 0; ks < 2; ++ks)
            a[mt][ks] = *(const bf16x8*)(w1bT + ((size_t)r * 48 + mt * 16 + row16) * 64 + ks * 32 + g * 8);
    int s = sortedR[e0 + row16].x;
    bf16x8 b0 = *(const bf16x8*)(hb + (size_t)s * 64 + g * 8);
    bf16x8 b1 = *(const bf16x8*)(hb + (size_t)s * 64 + 32 + g * 8);
    f32x4 acc[3];
#pragma unroll
    for (int mt = 0; mt < 3; ++mt) acc[mt] = (f32x4){0.f, 0.f, 0.f, 0.f};
#pragma unroll
    for (int mt = 0; mt < 3; ++mt) {
        acc[mt] = __builtin_amdgcn_mfma_f32_16x16x32_bf16(a[mt][0], b0, acc[mt], 0, 0, 0);
        acc[mt] = __builtin_amdgcn_mfma_f32_16x16x32_bf16(a[mt][1], b1, acc[mt], 0, 0, 0);
    }
    float* orow = outj1 + (size_t)(e0 + row16) * 40;
#pragma unroll
    for (int mt = 0; mt < 3; ++mt) {
        int col = mt * 16 + g * 4;
        if (col < 40) {
            float4 v; v.x = acc[mt][0]; v.y = acc[mt][1]; v.z = acc[mt][2]; v.w = acc[mt][3];
            *(float4*)(orow + col) = v;
        }
    }
}

// ---------------- conv1 aggregate + wave-local segment softmax ----------------
// alpha1s is dst-ordered (dense, EE entries) -> all alpha reads are linear.
__global__ __launch_bounds__(256) void k_aggr1(const int4* sortedD, const int* rowptrD,
                                               const float* outj1, const float* alpha1s,
                                               const float* wmod, const float* bias1,
                                               f16* h1h, u16* h1b) {
    __shared__ unsigned smax[4][RR * 4];
    __shared__ float    ssum[4][RR * 4];
    int wid = threadIdx.x >> 6;
    int lane = threadIdx.x & 63;
    int w = blockIdx.x * 4 + wid;       // grid = NN/4 exactly (NN % 4 == 0)
    int beg = rowptrD[w], end = rowptrD[w + 1];
    unsigned* mx = smax[wid];
    float*    sm = ssum[wid];
    // phase A: init table entries for relations present at this dst
    for (int j = beg + lane; j < end; j += 64) {
        int rb = sortedD[j].z * 4;
        mx[rb + 0] = ORD_NEGINF; mx[rb + 1] = ORD_NEGINF;
        mx[rb + 2] = ORD_NEGINF; mx[rb + 3] = ORD_NEGINF;
        sm[rb + 0] = 0.f; sm[rb + 1] = 0.f; sm[rb + 2] = 0.f; sm[rb + 3] = 0.f;
    }
    __syncthreads();
    // phase B: per-(rel,comp) max via LDS ordered-uint atomicMax
    for (int j = beg + lane; j < end; j += 64) {
        float4 a = *(const float4*)(alpha1s + (size_t)j * 4);
        int rb = sortedD[j].z * 4;
        atomicMax(&mx[rb + 0], f2ord(a.x));
        atomicMax(&mx[rb + 1], f2ord(a.y));
        atomicMax(&mx[rb + 2], f2ord(a.z));
        atomicMax(&mx[rb + 3], f2ord(a.w));
    }
    __syncthreads();
    // phase C: per-(rel,comp) sum of exp via LDS float atomicAdd
    for (int j = beg + lane; j < end; j += 64) {
        float4 a = *(const float4*)(alpha1s + (size_t)j * 4);
        int rb = sortedD[j].z * 4;
        atomicAdd(&sm[rb + 0], __expf(a.x - ord2f(mx[rb + 0])));
        atomicAdd(&sm[rb + 1], __expf(a.y - ord2f(mx[rb + 1])));
        atomicAdd(&sm[rb + 2], __expf(a.z - ord2f(mx[rb + 2])));
        atomicAdd(&sm[rb + 3], __expf(a.w - ord2f(mx[rb + 3])));
    }
    __syncthreads();
    // phase C2: sums -> reciprocals (touches stale entries harmlessly)
    for (int t = lane; t < RR * 4; t += 64) sm[t] = 1.f / (sm[t] + EPS);
    __syncthreads();
    // phase D: aggregate (channel-parallel, recompute exp per edge)
    int hh = lane >= 20 ? 1 : 0;
    int oo = lane - hh * 20;
    float acc0 = 0.f, acc1 = 0.f, accw = 0.f;
    if (lane < 40) {
        for (int j = beg; j < end; ++j) {
            int4 rec = sortedD[j];
            int i = rec.x, rb = rec.z * 4 + hh * 2;
            float v = outj1[(size_t)i * 40 + lane];
            float2 a = *(const float2*)(alpha1s + (size_t)j * 4 + hh * 2);
            float e0 = __expf(a.x - ord2f(mx[rb]));
            float e1 = __expf(a.y - ord2f(mx[rb + 1]));
            acc0 = fmaf(v, e0 * sm[rb], acc0);
            acc1 = fmaf(v, e1 * sm[rb + 1], acc1);
            accw += v;
        }
        float wm = wmod[oo];
        int b0 = hh * 40 + oo;
        float o0 = fmaxf(acc0 + wm * accw + bias1[b0], 0.f);
        float o1 = fmaxf(acc1 + wm * accw + bias1[b0 + 20], 0.f);
        // f16 row for conv2 attention gathers (f32-precision-critical path keeps f16)
        h1h[(size_t)w * 80 + b0]      = (f16)o0;
        h1h[(size_t)w * 80 + b0 + 20] = (f16)o1;
        // h1b[n][b(2)][c(64)]: b=hh, c=oo and oo+20 (MFMA layout, zero-padded)
        h1b[((size_t)w * 2 + hh) * 64 + oo]      = f2bf(o0);
        h1b[((size_t)w * 2 + hh) * 64 + oo + 20] = f2bf(o1);
    } else {
        int lam = lane - 40;   // 0..23 -> zero pads c=40..63 for both b
        h1b[((size_t)w * 2 + 0) * 64 + 40 + lam] = 0;
        h1b[((size_t)w * 2 + 1) * 64 + 40 + lam] = 0;
    }
}

// ---------------- conv2 attention logits (f16 gathers, f32 math) ----------
__device__ __forceinline__ void attn2_compute(const f16x8* hd, const f16x8* hs,
                                              const float* __restrict__ q,
                                              const float* __restrict__ k,
                                              float* a) {
    a[0] = 0.f; a[1] = 0.f;
#pragma unroll
    for (int cc = 0; cc < 10; ++cc) {     // 10 x f16x8 = 80 elems
        f16x8 xv = hd[cc], yv = hs[cc];
#pragma unroll
        for (int j = 0; j < 8; ++j) {
            float x = (float)xv[j];
            float y = (float)yv[j];
            int bc = cc * 8 + j;
            a[0] = fmaf(x, q[bc * 2 + 0], fmaf(y, k[bc * 2 + 0], a[0]));
            a[1] = fmaf(x, q[bc * 2 + 1], fmaf(y, k[bc * 2 + 1], a[1]));
        }
    }
}

// writes raw leaky-relu logits at dst-sorted position posD[i]
__global__ __launch_bounds__(256) void k_f1s(const int4* sortedR, const f16* h1h,
                                             const float* wq2g, const float* wk2g,
                                             const float* aeS, const int* posD,
                                             float* alpha2s) {
    __shared__ float qs[160], ks[160];
    int i = blockIdx.x * 256 + threadIdx.x;
    int4 ed = sortedR[i];
    int s = ed.x, d = ed.y, r = ed.z, e = ed.w;
    int rFirst = sortedR[(size_t)blockIdx.x * 256].z;
    int rLast  = sortedR[(size_t)blockIdx.x * 256 + 255].z;
    bool allsame = (rFirst == rLast);
    if (allsame && threadIdx.x < 160) {
        qs[threadIdx.x] = wq2g[(size_t)rFirst * 160 + threadIdx.x];
        ks[threadIdx.x] = wk2g[(size_t)rFirst * 160 + threadIdx.x];
    }
    __syncthreads();
    if (e < 0) return;   // dummy pad edge
    const f16x8* hd = (const f16x8*)(h1h + (size_t)d * 80);
    const f16x8* hs = (const f16x8*)(h1h + (size_t)s * 80);
    float a[2];
    if (allsame) attn2_compute(hd, hs, qs, ks, a);
    else         attn2_compute(hd, hs, wq2g + (size_t)r * 160, wk2g + (size_t)r * 160, a);
    float2 aev = *(const float2*)(aeS + (size_t)i * 2);   // linear (sorted order)
    a[0] += aev.x;
    a[1] += aev.y;
    a[0] = a[0] > 0.f ? a[0] : 0.2f * a[0];
    a[1] = a[1] > 0.f ? a[1] : 0.2f * a[1];
    float2 av; av.x = a[0]; av.y = a[1];
    *(float2*)(alpha2s + (size_t)posD[i] * 2) = av;
}

// ---------------- conv2 transform via MFMA (block-diagonal, K padded 40->64) -
__global__ __launch_bounds__(256) void k_mfma2(const int4* sortedR, const u16* h1b,
                                               const u16* w2bT, float* outj2) {
    int wid = threadIdx.x >> 6, l = threadIdx.x & 63;
    int base = blockIdx.x * 64;
    int r = sortedR[base].z;
    int e0 = base + wid * 16;
    int row16 = l & 15, g = l >> 4;
    bf16x8 a[2][2][2];   // [b][mt][ks]
#pragma unroll
    for (int b = 0; b < 2; ++b)
#pragma unroll
        for (int mt = 0; mt < 2; ++mt)
#pragma unroll
            for (int ks = 0; ks < 2; ++ks)
                a[b][mt][ks] = *(const bf16x8*)(w2bT + ((((size_t)r * 2 + b) * 32) + mt * 16 + row16) * 64 + ks * 32 + g * 8);
    int s = sortedR[e0 + row16].x;
    bf16x8 bb[2][2];
#pragma unroll
    for (int b = 0; b < 2; ++b)
#pragma unroll
        for (int ks = 0; ks < 2; ++ks)
            bb[b][ks] = *(const bf16x8*)(h1b + ((size_t)s * 2 + b) * 64 + ks * 32 + g * 8);
    f32x4 acc[2][2];
#pragma unroll
    for (int b = 0; b < 2; ++b)
#pragma unroll
        for (int mt = 0; mt < 2; ++mt) acc[b][mt] = (f32x4){0.f, 0.f, 0.f, 0.f};
#pragma unroll
    for (int b = 0; b < 2; ++b)
#pragma unroll
        for (int mt = 0; mt < 2; ++mt) {
            acc[b][mt] = __builtin_amdgcn_mfma_f32_16x16x32_bf16(a[b][mt][0], bb[b][0], acc[b][mt], 0, 0, 0);
            acc[b][mt] = __builtin_amdgcn_mfma_f32_16x16x32_bf16(a[b][mt][1], bb[b][1], acc[b][mt], 0, 0, 0);
        }
    float* orow = outj2 + (size_t)(e0 + row16) * 64;
#pragma unroll
    for (int b = 0; b < 2; ++b)
#pragma unroll
        for (int mt = 0; mt < 2; ++mt) {
            float4 v; v.x = acc[b][mt][0]; v.y = acc[b][mt][1]; v.z = acc[b][mt][2]; v.w = acc[b][mt][3];
            *(float4*)(orow + b * 32 + mt * 16 + g * 4) = v;
        }
}

// ---------------- conv2 aggregate + wave-local softmax (per-dst segments) ----
// alpha2s is dst-ordered -> linear reads.
__global__ __launch_bounds__(256) void k_aggr2(const int4* sortedD, const int* rowptrD,
                                               const float* outj2, const float* alpha2s,
                                               float* h2) {
    int w = blockIdx.x * 4 + (threadIdx.x >> 6);
    int lane = threadIdx.x & 63;
    if (w >= NN) return;
    int beg = rowptrD[w], end = rowptrD[w + 1];
    // phase B: per-dst max (2 comps) via lane-partial + shuffle reduce
    float m0 = -INFINITY, m1 = -INFINITY;
    for (int j = beg + lane; j < end; j += 64) {
        float2 a = *(const float2*)(alpha2s + (size_t)j * 2);
        m0 = fmaxf(m0, a.x); m1 = fmaxf(m1, a.y);
    }
#pragma unroll
    for (int off = 32; off; off >>= 1) {
        m0 = fmaxf(m0, __shfl_xor(m0, off));
        m1 = fmaxf(m1, __shfl_xor(m1, off));
    }
    // phase C: sum of exp
    float s0 = 0.f, s1 = 0.f;
    for (int j = beg + lane; j < end; j += 64) {
        float2 a = *(const float2*)(alpha2s + (size_t)j * 2);
        s0 += __expf(a.x - m0); s1 += __expf(a.y - m1);
    }
#pragma unroll
    for (int off = 32; off; off >>= 1) {
        s0 += __shfl_xor(s0, off);
        s1 += __shfl_xor(s1, off);
    }
    // phase D: aggregate (channel-parallel, recompute exp per edge)
    int b = lane >> 5;
    float mb = b ? m1 : m0;
    float rs = 1.f / ((b ? s1 : s0) + EPS);
    float acc = 0.f;
    for (int j = beg; j < end; ++j) {
        int i = sortedD[j].x;
        float v = outj2[(size_t)i * 64 + lane];
        float a = alpha2s[(size_t)j * 2 + b];
        acc = fmaf(v, __expf(a - mb) * rs, acc);
    }
    h2[(size_t)w * 64 + lane] = acc;
}

__global__ void k_out(const float* h2, const float* lin2_w, const float* lin2_b,
                      float* out) {
    int n = blockIdx.x * blockDim.x + threadIdx.x;
    if (n >= NN) return;
    float o[4] = {lin2_b[0], lin2_b[1], lin2_b[2], lin2_b[3]};
    const float* hr = h2 + (size_t)n * 64;
    for (int c = 0; c < 64; ++c) {
        float hv = hr[c];
#pragma unroll
        for (int t = 0; t < 4; ++t) o[t] = fmaf(hv, lin2_w[c * 4 + t], o[t]);
    }
    float m = fmaxf(fmaxf(o[0], o[1]), fmaxf(o[2], o[3]));
    float s = __expf(o[0] - m) + __expf(o[1] - m) + __expf(o[2] - m) + __expf(o[3] - m);
    float lse = m + logf(s);
#pragma unroll
    for (int t = 0; t < 4; ++t) out[(size_t)n * 4 + t] = o[t] - lse;
}

extern "C" void kernel_launch(void* const* d_in, const int* in_sizes, int n_in,
                              void* d_out, int out_size, void* d_ws, size_t ws_size,
                              hipStream_t stream) {
    const float* x        = (const float*)d_in[0];
    const int*   eidx     = (const int*)d_in[1];
    const int*   etype    = (const int*)d_in[2];
    const float* eattr    = (const float*)d_in[3];
    const float* lin1_w   = (const float*)d_in[4];
    const float* att1     = (const float*)d_in[5];
    const float* basis1   = (const float*)d_in[6];
    const float* q1       = (const float*)d_in[7];
    const float* k1       = (const float*)d_in[8];
    const float* wmod1    = (const float*)d_in[9];
    const float* bias1    = (const float*)d_in[10];
    const float* w2       = (const float*)d_in[11];
    const float* q2       = (const float*)d_in[12];
    const float* k2       = (const float*)d_in[13];
    const float* lew      = (const float*)d_in[14];
    const float* e2i      = (const float*)d_in[15];
    const float* lin2_w   = (const float*)d_in[16];
    const float* lin2_b   = (const float*)d_in[17];

    const int* src = eidx;
    const int* dst = eidx + EE;

    // ---------------- workspace layout (f32 units) ----------------
    float* W = (float*)d_ws;
    float* w1      = W;   W += 230400;
    float* wq1     = W;   W += 23040;
    float* wk1     = W;   W += 23040;
    float* wq2     = W;   W += 14400;
    float* wk2     = W;   W += 14400;
    float* we      = W;   W += 32;
    float* h2      = W;   W += (size_t)NN * 64;
    float* aeS     = W;   W += (size_t)E2 * 2;
    f16*   hh      = (f16*)W;   W += (size_t)NN * 64 / 2;        // N*64 f16 (logits)
    f16*   h1h     = (f16*)W;   W += (size_t)NN * 80 / 2;        // N*80 f16 (logits)
    u16*   hb      = (u16*)W;   W += (size_t)NN * 64 / 2;        // N*64 bf16 (MFMA)
    u16*   h1b     = (u16*)W;   W += (size_t)NN * 128 / 2;       // N*2*64 bf16 (MFMA)
    u16*   w1bT    = (u16*)W;   W += (size_t)RR * 48 * 64 / 2;
    u16*   w2bT    = (u16*)W;   W += (size_t)RR * 2 * 32 * 64 / 2;
    // union: conv1 {outj1[E2*40], alpha1s[EE*4]} / conv2 {outj2[E2*64]}
    // (outj2 overlaps alpha1s but is written only after k_aggr1 completes)
    float* uni     = W;   W += (size_t)E2 * 64;
    float* outj1   = uni;
    float* alpha1s = uni + (size_t)E2 * 40;
    float* outj2   = uni;
    float* alpha2s = W;   W += (size_t)EE * 2;
    int4*  sortedR = (int4*)W;
    int*   I = (int*)W;   I += (size_t)E2 * 4;
    int4*  sortedD = (int4*)I;  I += (size_t)E2 * 4;
    int*   posS    = I;   I += EE;
    int*   posD    = I;   I += E2;
    int*   rowptrD = I;   I += NN + 1;
    int*   cursorD = I;   I += NN;
    int*   histD   = I;   I += NN;    // zeroed block starts here
    int*   hist    = I;   I += 128;
    int*   cursor  = I;   I += 128;

    // ---------------- init ----------------
    hipMemsetAsync(histD, 0, (size_t)(NN + 256) * 4, stream);
    k_fillrec<<<E2 / 256, 256, 0, stream>>>(sortedR, E2);

    // sorts
    k_hist<<<EE / 256, 256, 0, stream>>>(etype, hist);
    k_scanPad<<<1, 64, 0, stream>>>(hist, cursor);
    k_scatter<<<EE / 256, 256, 0, stream>>>(src, dst, etype, cursor, sortedR, posS);
    k_histD<<<EE / 256, 256, 0, stream>>>(dst, histD);
    k_scanD<<<1, 256, 0, stream>>>(histD, rowptrD, cursorD);
    k_scatterD<<<E2 / 256, 256, 0, stream>>>(sortedR, cursorD, sortedD, posD);

    // folded weights + f16/bf16 prep + dense input layer + edge-attr logits
    k_w1<<<(RR * 2560 + 255) / 256, 256, 0, stream>>>(att1, basis1, w1);
    k_wqk1<<<(RR * 256 + 255) / 256, 256, 0, stream>>>(w1, q1, k1, wq1, wk1);
    k_wqk2<<<(RR * 160 + 255) / 256, 256, 0, stream>>>(w2, q2, k2, wq2, wk2);
    k_we<<<1, 32, 0, stream>>>(lew, e2i, we);
    k_ae<<<EE / 256, 256, 0, stream>>>(eattr, we, posS, aeS);
    k_w1bT<<<(RR * 48 * 64) / 256, 256, 0, stream>>>(w1, w1bT);
    k_w2bT<<<(RR * 2 * 32 * 64) / 256, 256, 0, stream>>>(w2, w2bT);
    k_h<<<NN, 64, 0, stream>>>(x, lin1_w, hh, hb);

    // conv1
    k_e1s<<<E2 / 256, 256, 0, stream>>>(sortedR, hh, wq1, wk1, posD, alpha1s);
    k_mfma1<<<E2 / 64, 256, 0, stream>>>(sortedR, hb, w1bT, outj1);
    k_aggr1<<<NN / 4, 256, 0, stream>>>(sortedD, rowptrD, outj1, alpha1s,
                                        wmod1, bias1, h1h, h1b);

    // conv2 (outj2 aliases dead conv1 buffers)
    k_f1s<<<E2 / 256, 256, 0, stream>>>(sortedR, h1h, wq2, wk2, aeS, posD, alpha2s);
    k_mfma2<<<E2 / 64, 256, 0, stream>>>(sortedR, h1b, w2bT, outj2);
    k_aggr2<<<(NN + 3) / 4, 256, 0, stream>>>(sortedD, rowptrD, outj2, alpha2s, h2);

    k_out<<<(NN + 255) / 256, 256, 0, stream>>>(h2, lin2_w, lin2_b, (float*)d_out);
}

// Round 5
// 640.527 us; speedup vs baseline: 1.2321x; 1.0917x over previous
//
#include <hip/hip_runtime.h>
#include <math.h>

constexpr int NN   = 20000;   // nodes
constexpr int EE   = 640000;  // edges
constexpr int RR   = 90;      // relations
constexpr int INF_ = 128;     // in features
constexpr int HID  = 64;      // hidden
constexpr float EPS = 1e-16f;
constexpr int E2   = 646144;  // padded edge capacity: 2524*256, >= EE + 90*63

typedef unsigned short u16;
typedef _Float16 f16;
typedef __attribute__((ext_vector_type(8))) short bf16x8;
typedef __attribute__((ext_vector_type(8))) _Float16 f16x8;
typedef __attribute__((ext_vector_type(4))) _Float16 f16x4;
typedef __attribute__((ext_vector_type(4))) float f32x4;

__device__ inline u16 f2bf(float f) {
    unsigned int u = __float_as_uint(f);
    unsigned int r = (u + 0x7FFFu + ((u >> 16) & 1u)) >> 16;
    return (u16)r;
}

// order-preserving float<->uint encode (monotone: f<g  <=>  f2ord(f)<f2ord(g))
__device__ inline unsigned f2ord(float f) {
    unsigned u = __float_as_uint(f);
    return (u & 0x80000000u) ? ~u : (u | 0x80000000u);
}
__device__ inline float ord2f(unsigned x) {
    unsigned u = (x & 0x80000000u) ? (x & 0x7FFFFFFFu) : ~x;
    return __uint_as_float(u);
}
// f2ord(-INF) = 0x007FFFFF — table init value
#define ORD_NEGINF 0x007FFFFFu

__global__ void k_fillrec(int4* p, int n) {
    int i = blockIdx.x * blockDim.x + threadIdx.x;
    if (i < n) { int4 r; r.x = 0; r.y = 0; r.z = 0; r.w = -1; p[i] = r; }
}

// ---------------- sort 1: by relation, segment-padded to 64 ----------------
__global__ void k_hist(const int* et, int* hist) {
    __shared__ int lh[RR];
    if (threadIdx.x < RR) lh[threadIdx.x] = 0;
    __syncthreads();
    int i = blockIdx.x * blockDim.x + threadIdx.x;
    if (i < EE) atomicAdd(&lh[et[i]], 1);
    __syncthreads();
    if (threadIdx.x < RR) atomicAdd(&hist[threadIdx.x], lh[threadIdx.x]);
}

__global__ void k_scanPad(const int* hist, int* cursor) {
    if (threadIdx.x == 0) {
        int acc = 0;
        for (int r = 0; r < RR; ++r) {
            cursor[r] = acc;
            acc += (hist[r] + 63) & ~63;   // pad each segment to 64
        }
    }
}

// sortedR records {src, dst, rel, orig}; dummies stay {0,0,0,-1}
// posS[orig] = relation-sorted position (for sorted ae scatter)
__global__ void k_scatter(const int* src, const int* dst, const int* et,
                          int* cursor, int4* sortedR, int* posS) {
    __shared__ int lh[RR];
    __shared__ int lbase[RR];
    if (threadIdx.x < RR) lh[threadIdx.x] = 0;
    __syncthreads();
    int i = blockIdx.x * blockDim.x + threadIdx.x;
    int r = et[i];
    int rank = atomicAdd(&lh[r], 1);
    __syncthreads();
    if (threadIdx.x < RR) {
        int c = lh[threadIdx.x];
        lbase[threadIdx.x] = c ? atomicAdd(&cursor[threadIdx.x], c) : 0;
    }
    __syncthreads();
    int pos = lbase[r] + rank;
    int4 rec; rec.x = src[i]; rec.y = dst[i]; rec.z = r; rec.w = i;
    sortedR[pos] = rec;
    posS[i] = pos;
}

// ---------------- sort 2: by destination ----------------
__global__ void k_histD(const int* dst, int* histD) {
    int i = blockIdx.x * blockDim.x + threadIdx.x;
    if (i < EE) atomicAdd(&histD[dst[i]], 1);
}

__global__ void k_scanD(const int* histD, int* rowptrD, int* cursorD) {
    __shared__ int part[256];
    const int CH = (NN + 255) / 256;
    int tid = threadIdx.x;
    int base = tid * CH;
    int s = 0;
    for (int j = 0; j < CH; ++j) {
        int idx = base + j;
        if (idx < NN) s += histD[idx];
    }
    part[tid] = s;
    __syncthreads();
    if (tid == 0) {
        int acc = 0;
        for (int t = 0; t < 256; ++t) { int v = part[t]; part[t] = acc; acc += v; }
    }
    __syncthreads();
    int acc = part[tid];
    for (int j = 0; j < CH; ++j) {
        int idx = base + j;
        if (idx < NN) {
            rowptrD[idx] = acc;
            cursorD[idx] = acc;
            acc += histD[idx];
        }
    }
    if (tid == 0) rowptrD[NN] = EE;
}

// posD[paddedpos] = dst-sorted position ; relD[dstpos] = relation (u16)
__global__ void k_scatterD(const int4* sortedR, int* cursorD, int* posD,
                           u16* relD) {
    int i = blockIdx.x * blockDim.x + threadIdx.x;
    if (i >= E2) return;
    int4 rec = sortedR[i];
    if (rec.w < 0) return;
    int pos = atomicAdd(&cursorD[rec.y], 1);
    posD[i] = pos;
    relD[pos] = (u16)rec.z;
}

// ---------------- weight folding ----------------
__global__ void k_w1(const float* att1, const float* basis1, float* w1) {
    int idx = blockIdx.x * blockDim.x + threadIdx.x;
    if (idx >= RR * 2560) return;
    int r = idx / 2560, co = idx - r * 2560;
    float acc = 0.f;
    for (int b = 0; b < 35; ++b) acc += att1[r * 35 + b] * basis1[b * 2560 + co];
    w1[idx] = acc;
}

__global__ void k_wqk1(const float* w1, const float* q1, const float* k1,
                       float* wq1, float* wk1) {
    int idx = blockIdx.x * blockDim.x + threadIdx.x;
    if (idx >= RR * 64 * 4) return;
    int t = idx & 3, c = (idx >> 2) & 63, r = idx >> 8;
    const float* wrow = w1 + (size_t)r * 2560 + c * 40;
    float aq = 0.f, ak = 0.f;
    for (int o = 0; o < 40; ++o) {
        float w = wrow[o];
        aq += w * q1[o * 4 + t];
        ak += w * k1[o * 4 + t];
    }
    wq1[idx] = aq; wk1[idx] = ak;
}

__global__ void k_wqk2(const float* w2, const float* q2, const float* k2,
                       float* wq2, float* wk2) {
    int idx = blockIdx.x * blockDim.x + threadIdx.x;
    if (idx >= RR * 80 * 2) return;
    int t = idx & 1, bc = (idx >> 1) % 80, r = idx / 160;
    int b = bc / 40, c = bc % 40;
    const float* wbase = w2 + (size_t)((r * 2 + b) * 40 + c) * 32;
    float aq = 0.f, ak = 0.f;
    for (int d = 0; d < 32; ++d) {
        float w = wbase[d];
        aq += w * q2[(b * 32 + d) * 2 + t];
        ak += w * k2[(b * 32 + d) * 2 + t];
    }
    wq2[idx] = aq; wk2[idx] = ak;
}

__global__ void k_we(const float* lew, const float* e2, float* we) {
    int idx = threadIdx.x;
    if (idx >= 32) return;
    int i = idx >> 1, t = idx & 1;
    float acc = 0.f;
    for (int j = 0; j < 64; ++j) acc += lew[i * 64 + j] * e2[j * 2 + t];
    we[idx] = acc;
}

// aeS[posS[e]][2] = edge_attr[e] @ we  — coalesced read, scattered 8B write
__global__ __launch_bounds__(256) void k_ae(const float* ea, const float* weg,
                                            const int* posS, float* aeS) {
    __shared__ float wes[32];
    if (threadIdx.x < 32) wes[threadIdx.x] = weg[threadIdx.x];
    __syncthreads();
    int e = blockIdx.x * 256 + threadIdx.x;
    if (e >= EE) return;
    const float4* ep = (const float4*)(ea + (size_t)e * 16);
    float a0 = 0.f, a1 = 0.f;
#pragma unroll
    for (int cc = 0; cc < 4; ++cc) {
        float4 v = ep[cc];
        const float* vv = (const float*)&v;
#pragma unroll
        for (int j = 0; j < 4; ++j) {
            int ii = cc * 4 + j;
            a0 = fmaf(vv[j], wes[ii * 2 + 0], a0);
            a1 = fmaf(vv[j], wes[ii * 2 + 1], a1);
        }
    }
    float2 av; av.x = a0; av.y = a1;
    *(float2*)(aeS + (size_t)posS[e] * 2) = av;
}

// bf16 transposed+padded weights: w1bT[r][o(48)][k(64)]
__global__ void k_w1bT(const float* w1, u16* w1bT) {
    int idx = blockIdx.x * blockDim.x + threadIdx.x;
    if (idx >= RR * 48 * 64) return;
    int k = idx & 63, o = (idx >> 6) % 48, r = idx / (48 * 64);
    float v = (o < 40) ? w1[(size_t)r * 2560 + k * 40 + o] : 0.f;
    w1bT[idx] = f2bf(v);
}

// w2bT[r][b][d(32)][c(64)]  (c padded 40->64 with zeros)
__global__ void k_w2bT(const float* w2, u16* w2bT) {
    int idx = blockIdx.x * blockDim.x + threadIdx.x;
    if (idx >= RR * 2 * 32 * 64) return;
    int c = idx & 63, d = (idx >> 6) & 31, b = (idx >> 11) & 1, r = idx >> 12;
    float v = (c < 40) ? w2[((((size_t)r * 2 + b) * 40) + c) * 32 + d] : 0.f;
    w2bT[idx] = f2bf(v);
}

// hh = f16(x @ lin1_w) for logit gathers ; hb = bf16 copy for MFMA
__global__ void k_h(const float* x, const float* lin1_w, f16* hh, u16* hb) {
    __shared__ float xs[INF_];
    int n = blockIdx.x, t = threadIdx.x;
    xs[t]      = x[(size_t)n * INF_ + t];
    xs[t + 64] = x[(size_t)n * INF_ + t + 64];
    __syncthreads();
    float acc = 0.f;
    for (int i = 0; i < INF_; ++i) acc += xs[i] * lin1_w[i * HID + t];
    hh[(size_t)n * HID + t] = (f16)acc;
    hb[(size_t)n * HID + t] = f2bf(acc);
}

// ---------------- conv1 attention logits (f16 gathers, f32 math) ----------
__device__ __forceinline__ void attn1_compute(const f16x8* hd, const f16x8* hs,
                                              const float* __restrict__ q,
                                              const float* __restrict__ k,
                                              float* qi, float* kj) {
#pragma unroll
    for (int t = 0; t < 4; ++t) { qi[t] = 0.f; kj[t] = 0.f; }
#pragma unroll
    for (int cc = 0; cc < 8; ++cc) {       // 8 x f16x8 = 64 elems
        f16x8 a = hd[cc], b = hs[cc];
#pragma unroll
        for (int j = 0; j < 8; ++j) {
            float av = (float)a[j];
            float bv = (float)b[j];
            const float* q4 = q + (cc * 8 + j) * 4;
            const float* k4 = k + (cc * 8 + j) * 4;
#pragma unroll
            for (int t = 0; t < 4; ++t) {
                qi[t] = fmaf(av, q4[t], qi[t]);
                kj[t] = fmaf(bv, k4[t], kj[t]);
            }
        }
    }
}

// writes raw logits at dst-sorted position posD[i]
__global__ __launch_bounds__(256) void k_e1s(const int4* sortedR, const f16* hh,
                                             const float* wq1g, const float* wk1g,
                                             const int* posD, float* alpha1s) {
    __shared__ float qs[256], ks[256];
    int i = blockIdx.x * 256 + threadIdx.x;
    int4 ed = sortedR[i];
    int s = ed.x, d = ed.y, r = ed.z;
    int rFirst = sortedR[(size_t)blockIdx.x * 256].z;
    int rLast  = sortedR[(size_t)blockIdx.x * 256 + 255].z;
    bool allsame = (rFirst == rLast);
    if (allsame) {
        qs[threadIdx.x] = wq1g[(size_t)rFirst * 256 + threadIdx.x];
        ks[threadIdx.x] = wk1g[(size_t)rFirst * 256 + threadIdx.x];
    }
    __syncthreads();
    if (ed.w < 0) return;   // dummy pad edge
    const f16x8* hd = (const f16x8*)(hh + (size_t)d * 64);
    const f16x8* hs = (const f16x8*)(hh + (size_t)s * 64);
    float qi[4], kj[4];
    if (allsame) attn1_compute(hd, hs, qs, ks, qi, kj);
    else         attn1_compute(hd, hs, wq1g + (size_t)r * 256, wk1g + (size_t)r * 256, qi, kj);
    float4 av;
    av.x = qi[0] * kj[0];
    av.y = qi[1] * kj[1];
    av.z = qi[2] * kj[2];
    av.w = qi[3] * kj[3];
    *(float4*)(alpha1s + (size_t)posD[i] * 4) = av;
}

// ---------------- conv1 transform via MFMA -> f16 rows at dst-sorted pos ----
__global__ __launch_bounds__(256) void k_mfma1(const int4* sortedR, const int* posD,
                                               const u16* hb, const u16* w1bT,
                                               f16* outj1h) {
    int wid = threadIdx.x >> 6, l = threadIdx.x & 63;
    int base = blockIdx.x * 64;
    int r = sortedR[base].z;
    int e0 = base + wid * 16;
    int row16 = l & 15, g = l >> 4;
    bf16x8 a[3][2];
#pragma unroll
    for (int mt = 0; mt < 3; ++mt)
#pragma unroll
        for (int ks = 0; ks < 2; ++ks)
            a[mt][ks] = *(const bf16x8*)(w1bT + ((size_t)r * 48 + mt * 16 + row16) * 64 + ks * 32 + g * 8);
    int4 er = sortedR[e0 + row16];
    int s = er.x;
    bf16x8 b0 = *(const bf16x8*)(hb + (size_t)s * 64 + g * 8);
    bf16x8 b1 = *(const bf16x8*)(hb + (size_t)s * 64 + 32 + g * 8);
    f32x4 acc[3];
#pragma unroll
    for (int mt = 0; mt < 3; ++mt) acc[mt] = (f32x4){0.f, 0.f, 0.f, 0.f};
#pragma unroll
    for (int mt = 0; mt < 3; ++mt) {
        acc[mt] = __builtin_amdgcn_mfma_f32_16x16x32_bf16(a[mt][0], b0, acc[mt], 0, 0, 0);
        acc[mt] = __builtin_amdgcn_mfma_f32_16x16x32_bf16(a[mt][1], b1, acc[mt], 0, 0, 0);
    }
    if (er.w < 0) return;   // dummy pad edge: no output row
    int pd = posD[e0 + row16];
    f16* orow = outj1h + (size_t)pd * 40;
#pragma unroll
    for (int mt = 0; mt < 3; ++mt) {
        int col = mt * 16 + g * 4;
        if (col < 40) {
            f16x4 v;
            v[0] = (f16)acc[mt][0]; v[1] = (f16)acc[mt][1];
            v[2] = (f16)acc[mt][2]; v[3] = (f16)acc[mt][3];
            *(f16x4*)(orow + col) = v;
        }
    }
}

// ---------------- conv1 aggregate + wave-local segment softmax ----------------
// alpha1s, outj1h, relD all dst-ordered -> fully linear reads.
// softmax table stride 5 -> rel spreads across all 32 LDS banks.
__global__ __launch_bounds__(256) void k_aggr1(const u16* relD, const int* rowptrD,
                                               const f16* outj1h, const float* alpha1s,
                                               const float* wmod, const float* bias1,
                                               f16* h1h, u16* h1b) {
    __shared__ unsigned smax[4][RR * 5];
    __shared__ float    ssum[4][RR * 5];
    int wid = threadIdx.x >> 6;
    int lane = threadIdx.x & 63;
    int w = blockIdx.x * 4 + wid;       // grid = NN/4 exactly (NN % 4 == 0)
    int beg = rowptrD[w], end = rowptrD[w + 1];
    unsigned* mx = smax[wid];
    float*    sm = ssum[wid];
    // phase A: init table entries for relations present at this dst
    for (int j = beg + lane; j < end; j += 64) {
        int rb = relD[j] * 5;
        mx[rb + 0] = ORD_NEGINF; mx[rb + 1] = ORD_NEGINF;
        mx[rb + 2] = ORD_NEGINF; mx[rb + 3] = ORD_NEGINF;
        sm[rb + 0] = 0.f; sm[rb + 1] = 0.f; sm[rb + 2] = 0.f; sm[rb + 3] = 0.f;
    }
    __syncthreads();
    // phase B: per-(rel,comp) max via LDS ordered-uint atomicMax
    for (int j = beg + lane; j < end; j += 64) {
        float4 a = *(const float4*)(alpha1s + (size_t)j * 4);
        int rb = relD[j] * 5;
        atomicMax(&mx[rb + 0], f2ord(a.x));
        atomicMax(&mx[rb + 1], f2ord(a.y));
        atomicMax(&mx[rb + 2], f2ord(a.z));
        atomicMax(&mx[rb + 3], f2ord(a.w));
    }
    __syncthreads();
    // phase C: per-(rel,comp) sum of exp via LDS float atomicAdd
    for (int j = beg + lane; j < end; j += 64) {
        float4 a = *(const float4*)(alpha1s + (size_t)j * 4);
        int rb = relD[j] * 5;
        atomicAdd(&sm[rb + 0], __expf(a.x - ord2f(mx[rb + 0])));
        atomicAdd(&sm[rb + 1], __expf(a.y - ord2f(mx[rb + 1])));
        atomicAdd(&sm[rb + 2], __expf(a.z - ord2f(mx[rb + 2])));
        atomicAdd(&sm[rb + 3], __expf(a.w - ord2f(mx[rb + 3])));
    }
    __syncthreads();
    // phase C2: sums -> reciprocals (touches stale entries harmlessly)
    for (int t = lane; t < RR * 5; t += 64) sm[t] = 1.f / (sm[t] + EPS);
    __syncthreads();
    // phase D: aggregate (channel-parallel, recompute exp per edge)
    int hh2 = lane >= 20 ? 1 : 0;
    int oo = lane - hh2 * 20;
    float acc0 = 0.f, acc1 = 0.f, accw = 0.f;
    if (lane < 40) {
        for (int j = beg; j < end; ++j) {
            int rb = relD[j] * 5 + hh2 * 2;
            float v = (float)outj1h[(size_t)j * 40 + lane];
            float2 a = *(const float2*)(alpha1s + (size_t)j * 4 + hh2 * 2);
            float e0 = __expf(a.x - ord2f(mx[rb]));
            float e1 = __expf(a.y - ord2f(mx[rb + 1]));
            acc0 = fmaf(v, e0 * sm[rb], acc0);
            acc1 = fmaf(v, e1 * sm[rb + 1], acc1);
            accw += v;
        }
        float wm = wmod[oo];
        int b0 = hh2 * 40 + oo;
        float o0 = fmaxf(acc0 + wm * accw + bias1[b0], 0.f);
        float o1 = fmaxf(acc1 + wm * accw + bias1[b0 + 20], 0.f);
        // f16 row for conv2 attention gathers
        h1h[(size_t)w * 80 + b0]      = (f16)o0;
        h1h[(size_t)w * 80 + b0 + 20] = (f16)o1;
        // h1b[n][b(2)][c(64)]: b=hh2, c=oo and oo+20 (MFMA layout, zero-padded)
        h1b[((size_t)w * 2 + hh2) * 64 + oo]      = f2bf(o0);
        h1b[((size_t)w * 2 + hh2) * 64 + oo + 20] = f2bf(o1);
    } else {
        int lam = lane - 40;   // 0..23 -> zero pads c=40..63 for both b
        h1b[((size_t)w * 2 + 0) * 64 + 40 + lam] = 0;
        h1b[((size_t)w * 2 + 1) * 64 + 40 + lam] = 0;
    }
}

// ---------------- conv2 attention logits (f16 gathers, f32 math) ----------
__device__ __forceinline__ void attn2_compute(const f16x8* hd, const f16x8* hs,
                                              const float* __restrict__ q,
                                              const float* __restrict__ k,
                                              float* a) {
    a[0] = 0.f; a[1] = 0.f;
#pragma unroll
    for (int cc = 0; cc < 10; ++cc) {     // 10 x f16x8 = 80 elems
        f16x8 xv = hd[cc], yv = hs[cc];
#pragma unroll
        for (int j = 0; j < 8; ++j) {
            float x = (float)xv[j];
            float y = (float)yv[j];
            int bc = cc * 8 + j;
            a[0] = fmaf(x, q[bc * 2 + 0], fmaf(y, k[bc * 2 + 0], a[0]));
            a[1] = fmaf(x, q[bc * 2 + 1], fmaf(y, k[bc * 2 + 1], a[1]));
        }
    }
}

// writes raw leaky-relu logits at dst-sorted position posD[i]
__global__ __launch_bounds__(256) void k_f1s(const int4* sortedR, const f16* h1h,
                                             const float* wq2g, const float* wk2g,
                                             const float* aeS, const int* posD,
                                             float* alpha2s) {
    __shared__ float qs[160], ks[160];
    int i = blockIdx.x * 256 + threadIdx.x;
    int4 ed = sortedR[i];
    int s = ed.x, d = ed.y, r = ed.z, e = ed.w;
    int rFirst = sortedR[(size_t)blockIdx.x * 256].z;
    int rLast  = sortedR[(size_t)blockIdx.x * 256 + 255].z;
    bool allsame = (rFirst == rLast);
    if (allsame && threadIdx.x < 160) {
        qs[threadIdx.x] = wq2g[(size_t)rFirst * 160 + threadIdx.x];
        ks[threadIdx.x] = wk2g[(size_t)rFirst * 160 + threadIdx.x];
    }
    __syncthreads();
    if (e < 0) return;   // dummy pad edge
    const f16x8* hd = (const f16x8*)(h1h + (size_t)d * 80);
    const f16x8* hs = (const f16x8*)(h1h + (size_t)s * 80);
    float a[2];
    if (allsame) attn2_compute(hd, hs, qs, ks, a);
    else         attn2_compute(hd, hs, wq2g + (size_t)r * 160, wk2g + (size_t)r * 160, a);
    float2 aev = *(const float2*)(aeS + (size_t)i * 2);   // linear (sorted order)
    a[0] += aev.x;
    a[1] += aev.y;
    a[0] = a[0] > 0.f ? a[0] : 0.2f * a[0];
    a[1] = a[1] > 0.f ? a[1] : 0.2f * a[1];
    float2 av; av.x = a[0]; av.y = a[1];
    *(float2*)(alpha2s + (size_t)posD[i] * 2) = av;
}

// ---------------- conv2 transform via MFMA -> f16 rows at dst-sorted pos ----
__global__ __launch_bounds__(256) void k_mfma2(const int4* sortedR, const int* posD,
                                               const u16* h1b, const u16* w2bT,
                                               f16* outj2h) {
    int wid = threadIdx.x >> 6, l = threadIdx.x & 63;
    int base = blockIdx.x * 64;
    int r = sortedR[base].z;
    int e0 = base + wid * 16;
    int row16 = l & 15, g = l >> 4;
    bf16x8 a[2][2][2];   // [b][mt][ks]
#pragma unroll
    for (int b = 0; b < 2; ++b)
#pragma unroll
        for (int mt = 0; mt < 2; ++mt)
#pragma unroll
            for (int ks = 0; ks < 2; ++ks)
                a[b][mt][ks] = *(const bf16x8*)(w2bT + ((((size_t)r * 2 + b) * 32) + mt * 16 + row16) * 64 + ks * 32 + g * 8);
    int4 er = sortedR[e0 + row16];
    int s = er.x;
    bf16x8 bb[2][2];
#pragma unroll
    for (int b = 0; b < 2; ++b)
#pragma unroll
        for (int ks = 0; ks < 2; ++ks)
            bb[b][ks] = *(const bf16x8*)(h1b + ((size_t)s * 2 + b) * 64 + ks * 32 + g * 8);
    f32x4 acc[2][2];
#pragma unroll
    for (int b = 0; b < 2; ++b)
#pragma unroll
        for (int mt = 0; mt < 2; ++mt) acc[b][mt] = (f32x4){0.f, 0.f, 0.f, 0.f};
#pragma unroll
    for (int b = 0; b < 2; ++b)
#pragma unroll
        for (int mt = 0; mt < 2; ++mt) {
            acc[b][mt] = __builtin_amdgcn_mfma_f32_16x16x32_bf16(a[b][mt][0], bb[b][0], acc[b][mt], 0, 0, 0);
            acc[b][mt] = __builtin_amdgcn_mfma_f32_16x16x32_bf16(a[b][mt][1], bb[b][1], acc[b][mt], 0, 0, 0);
        }
    if (er.w < 0) return;   // dummy pad edge
    int pd = posD[e0 + row16];
    f16* orow = outj2h + (size_t)pd * 64;
#pragma unroll
    for (int b = 0; b < 2; ++b)
#pragma unroll
        for (int mt = 0; mt < 2; ++mt) {
            f16x4 v;
            v[0] = (f16)acc[b][mt][0]; v[1] = (f16)acc[b][mt][1];
            v[2] = (f16)acc[b][mt][2]; v[3] = (f16)acc[b][mt][3];
            *(f16x4*)(orow + b * 32 + mt * 16 + g * 4) = v;
        }
}

// ---------------- conv2 aggregate + wave-local softmax (per-dst segments) ----
// alpha2s and outj2h dst-ordered -> fully linear reads, no index array needed.
__global__ __launch_bounds__(256) void k_aggr2(const int* rowptrD, const f16* outj2h,
                                               const float* alpha2s, float* h2) {
    int w = blockIdx.x * 4 + (threadIdx.x >> 6);
    int lane = threadIdx.x & 63;
    if (w >= NN) return;
    int beg = rowptrD[w], end = rowptrD[w + 1];
    // phase B: per-dst max (2 comps) via lane-partial + shuffle reduce
    float m0 = -INFINITY, m1 = -INFINITY;
    for (int j = beg + lane; j < end; j += 64) {
        float2 a = *(const float2*)(alpha2s + (size_t)j * 2);
        m0 = fmaxf(m0, a.x); m1 = fmaxf(m1, a.y);
    }
#pragma unroll
    for (int off = 32; off; off >>= 1) {
        m0 = fmaxf(m0, __shfl_xor(m0, off));
        m1 = fmaxf(m1, __shfl_xor(m1, off));
    }
    // phase C: sum of exp
    float s0 = 0.f, s1 = 0.f;
    for (int j = beg + lane; j < end; j += 64) {
        float2 a = *(const float2*)(alpha2s + (size_t)j * 2);
        s0 += __expf(a.x - m0); s1 += __expf(a.y - m1);
    }
#pragma unroll
    for (int off = 32; off; off >>= 1) {
        s0 += __shfl_xor(s0, off);
        s1 += __shfl_xor(s1, off);
    }
    // phase D: aggregate (channel-parallel, recompute exp per edge)
    int b = lane >> 5;
    float mb = b ? m1 : m0;
    float rs = 1.f / ((b ? s1 : s0) + EPS);
    float acc = 0.f;
    for (int j = beg; j < end; ++j) {
        float v = (float)outj2h[(size_t)j * 64 + lane];
        float a = alpha2s[(size_t)j * 2 + b];
        acc = fmaf(v, __expf(a - mb) * rs, acc);
    }
    h2[(size_t)w * 64 + lane] = acc;
}

__global__ void k_out(const float* h2, const float* lin2_w, const float* lin2_b,
                      float* out) {
    int n = blockIdx.x * blockDim.x + threadIdx.x;
    if (n >= NN) return;
    float o[4] = {lin2_b[0], lin2_b[1], lin2_b[2], lin2_b[3]};
    const float* hr = h2 + (size_t)n * 64;
    for (int c = 0; c < 64; ++c) {
        float hv = hr[c];
#pragma unroll
        for (int t = 0; t < 4; ++t) o[t] = fmaf(hv, lin2_w[c * 4 + t], o[t]);
    }
    float m = fmaxf(fmaxf(o[0], o[1]), fmaxf(o[2], o[3]));
    float s = __expf(o[0] - m) + __expf(o[1] - m) + __expf(o[2] - m) + __expf(o[3] - m);
    float lse = m + logf(s);
#pragma unroll
    for (int t = 0; t < 4; ++t) out[(size_t)n * 4 + t] = o[t] - lse;
}

extern "C" void kernel_launch(void* const* d_in, const int* in_sizes, int n_in,
                              void* d_out, int out_size, void* d_ws, size_t ws_size,
                              hipStream_t stream) {
    const float* x        = (const float*)d_in[0];
    const int*   eidx     = (const int*)d_in[1];
    const int*   etype    = (const int*)d_in[2];
    const float* eattr    = (const float*)d_in[3];
    const float* lin1_w   = (const float*)d_in[4];
    const float* att1     = (const float*)d_in[5];
    const float* basis1   = (const float*)d_in[6];
    const float* q1       = (const float*)d_in[7];
    const float* k1       = (const float*)d_in[8];
    const float* wmod1    = (const float*)d_in[9];
    const float* bias1    = (const float*)d_in[10];
    const float* w2       = (const float*)d_in[11];
    const float* q2       = (const float*)d_in[12];
    const float* k2       = (const float*)d_in[13];
    const float* lew      = (const float*)d_in[14];
    const float* e2i      = (const float*)d_in[15];
    const float* lin2_w   = (const float*)d_in[16];
    const float* lin2_b   = (const float*)d_in[17];

    const int* src = eidx;
    const int* dst = eidx + EE;

    // ---------------- workspace layout (f32 units) ----------------
    float* W = (float*)d_ws;
    float* w1      = W;   W += 230400;
    float* wq1     = W;   W += 23040;
    float* wk1     = W;   W += 23040;
    float* wq2     = W;   W += 14400;
    float* wk2     = W;   W += 14400;
    float* we      = W;   W += 32;
    float* h2      = W;   W += (size_t)NN * 64;
    float* aeS     = W;   W += (size_t)E2 * 2;
    f16*   hh      = (f16*)W;   W += (size_t)NN * 64 / 2;        // N*64 f16 (logits)
    f16*   h1h     = (f16*)W;   W += (size_t)NN * 80 / 2;        // N*80 f16 (logits)
    u16*   hb      = (u16*)W;   W += (size_t)NN * 64 / 2;        // N*64 bf16 (MFMA)
    u16*   h1b     = (u16*)W;   W += (size_t)NN * 128 / 2;       // N*2*64 bf16 (MFMA)
    u16*   w1bT    = (u16*)W;   W += (size_t)RR * 48 * 64 / 2;
    u16*   w2bT    = (u16*)W;   W += (size_t)RR * 2 * 32 * 64 / 2;
    // union region: conv1 {outj1h[EE*40 f16], alpha1s[EE*4 f32]} / conv2 {outj2h[EE*64 f16]}
    float* uni     = W;   W += (size_t)EE * 20 + (size_t)EE * 4;  // 24 f32-units/edge
    f16*   outj1h  = (f16*)uni;
    float* alpha1s = uni + (size_t)EE * 20;
    f16*   outj2h  = (f16*)uni;            // EE*64 f16 = EE*32 f32 > EE*24 -> extend below
    W += (size_t)EE * 8;                   // pad union to EE*32 f32 for outj2h
    float* alpha2s = W;   W += (size_t)EE * 2;
    int4*  sortedR = (int4*)W;
    int*   I = (int*)W;   I += (size_t)E2 * 4;
    u16*   relD    = (u16*)I;   I += (size_t)E2 / 2;
    int*   posS    = I;   I += EE;
    int*   posD    = I;   I += E2;
    int*   rowptrD = I;   I += NN + 1;
    int*   cursorD = I;   I += NN;
    int*   histD   = I;   I += NN;    // zeroed block starts here
    int*   hist    = I;   I += 128;
    int*   cursor  = I;   I += 128;

    // ---------------- init ----------------
    hipMemsetAsync(histD, 0, (size_t)(NN + 256) * 4, stream);
    k_fillrec<<<E2 / 256, 256, 0, stream>>>(sortedR, E2);

    // sorts
    k_hist<<<EE / 256, 256, 0, stream>>>(etype, hist);
    k_scanPad<<<1, 64, 0, stream>>>(hist, cursor);
    k_scatter<<<EE / 256, 256, 0, stream>>>(src, dst, etype, cursor, sortedR, posS);
    k_histD<<<EE / 256, 256, 0, stream>>>(dst, histD);
    k_scanD<<<1, 256, 0, stream>>>(histD, rowptrD, cursorD);
    k_scatterD<<<E2 / 256, 256, 0, stream>>>(sortedR, cursorD, posD, relD);

    // folded weights + f16/bf16 prep + dense input layer + edge-attr logits
    k_w1<<<(RR * 2560 + 255) / 256, 256, 0, stream>>>(att1, basis1, w1);
    k_wqk1<<<(RR * 256 + 255) / 256, 256, 0, stream>>>(w1, q1, k1, wq1, wk1);
    k_wqk2<<<(RR * 160 + 255) / 256, 256, 0, stream>>>(w2, q2, k2, wq2, wk2);
    k_we<<<1, 32, 0, stream>>>(lew, e2i, we);
    k_ae<<<EE / 256, 256, 0, stream>>>(eattr, we, posS, aeS);
    k_w1bT<<<(RR * 48 * 64) / 256, 256, 0, stream>>>(w1, w1bT);
    k_w2bT<<<(RR * 2 * 32 * 64) / 256, 256, 0, stream>>>(w2, w2bT);
    k_h<<<NN, 64, 0, stream>>>(x, lin1_w, hh, hb);

    // conv1
    k_e1s<<<E2 / 256, 256, 0, stream>>>(sortedR, hh, wq1, wk1, posD, alpha1s);
    k_mfma1<<<E2 / 64, 256, 0, stream>>>(sortedR, posD, hb, w1bT, outj1h);
    k_aggr1<<<NN / 4, 256, 0, stream>>>(relD, rowptrD, outj1h, alpha1s,
                                        wmod1, bias1, h1h, h1b);

    // conv2 (outj2h aliases dead conv1 buffers)
    k_f1s<<<E2 / 256, 256, 0, stream>>>(sortedR, h1h, wq2, wk2, aeS, posD, alpha2s);
    k_mfma2<<<E2 / 64, 256, 0, stream>>>(sortedR, posD, h1b, w2bT, outj2h);
    k_aggr2<<<(NN + 3) / 4, 256, 0, stream>>>(rowptrD, outj2h, alpha2s, h2);

    k_out<<<(NN + 255) / 256, 256, 0, stream>>>(h2, lin2_w, lin2_b, (float*)d_out);
}

// Round 6
// 602.987 us; speedup vs baseline: 1.3088x; 1.0623x over previous
//
#include <hip/hip_runtime.h>
#include <math.h>

constexpr int NN   = 20000;   // nodes
constexpr int EE   = 640000;  // edges
constexpr int RR   = 90;      // relations
constexpr int INF_ = 128;     // in features
constexpr int HID  = 64;      // hidden
constexpr float EPS = 1e-16f;
constexpr int E2   = 646144;  // padded edge capacity: 2524*256, >= EE + 90*63

typedef unsigned short u16;
typedef _Float16 f16;
typedef __attribute__((ext_vector_type(8))) _Float16 f16x8;
typedef __attribute__((ext_vector_type(4))) _Float16 f16x4;
typedef __attribute__((ext_vector_type(4))) float f32x4;

// order-preserving float<->uint encode (monotone: f<g  <=>  f2ord(f)<f2ord(g))
__device__ inline unsigned f2ord(float f) {
    unsigned u = __float_as_uint(f);
    return (u & 0x80000000u) ? ~u : (u | 0x80000000u);
}
__device__ inline float ord2f(unsigned x) {
    unsigned u = (x & 0x80000000u) ? (x & 0x7FFFFFFFu) : ~x;
    return __uint_as_float(u);
}
// f2ord(-INF) = 0x007FFFFF — table init value
#define ORD_NEGINF 0x007FFFFFu

__global__ void k_fillrec(int4* p, int n) {
    int i = blockIdx.x * blockDim.x + threadIdx.x;
    if (i < n) { int4 r; r.x = 0; r.y = 0; r.z = 0; r.w = -1; p[i] = r; }
}

// ---------------- sort 1: by relation, segment-padded to 64 ----------------
__global__ void k_hist(const int* et, int* hist) {
    __shared__ int lh[RR];
    if (threadIdx.x < RR) lh[threadIdx.x] = 0;
    __syncthreads();
    int i = blockIdx.x * blockDim.x + threadIdx.x;
    if (i < EE) atomicAdd(&lh[et[i]], 1);
    __syncthreads();
    if (threadIdx.x < RR) atomicAdd(&hist[threadIdx.x], lh[threadIdx.x]);
}

__global__ void k_scanPad(const int* hist, int* cursor) {
    if (threadIdx.x == 0) {
        int acc = 0;
        for (int r = 0; r < RR; ++r) {
            cursor[r] = acc;
            acc += (hist[r] + 63) & ~63;   // pad each segment to 64
        }
    }
}

// sortedR records {src, dst, rel, orig}; dummies stay {0,0,0,-1}
// posS[orig] = relation-sorted position (for sorted ae scatter)
__global__ void k_scatter(const int* src, const int* dst, const int* et,
                          int* cursor, int4* sortedR, int* posS) {
    __shared__ int lh[RR];
    __shared__ int lbase[RR];
    if (threadIdx.x < RR) lh[threadIdx.x] = 0;
    __syncthreads();
    int i = blockIdx.x * blockDim.x + threadIdx.x;
    int r = et[i];
    int rank = atomicAdd(&lh[r], 1);
    __syncthreads();
    if (threadIdx.x < RR) {
        int c = lh[threadIdx.x];
        lbase[threadIdx.x] = c ? atomicAdd(&cursor[threadIdx.x], c) : 0;
    }
    __syncthreads();
    int pos = lbase[r] + rank;
    int4 rec; rec.x = src[i]; rec.y = dst[i]; rec.z = r; rec.w = i;
    sortedR[pos] = rec;
    posS[i] = pos;
}

// ---------------- sort 2: by destination ----------------
__global__ void k_histD(const int* dst, int* histD) {
    int i = blockIdx.x * blockDim.x + threadIdx.x;
    if (i < EE) atomicAdd(&histD[dst[i]], 1);
}

__global__ void k_scanD(const int* histD, int* rowptrD, int* cursorD) {
    __shared__ int part[256];
    const int CH = (NN + 255) / 256;
    int tid = threadIdx.x;
    int base = tid * CH;
    int s = 0;
    for (int j = 0; j < CH; ++j) {
        int idx = base + j;
        if (idx < NN) s += histD[idx];
    }
    part[tid] = s;
    __syncthreads();
    if (tid == 0) {
        int acc = 0;
        for (int t = 0; t < 256; ++t) { int v = part[t]; part[t] = acc; acc += v; }
    }
    __syncthreads();
    int acc = part[tid];
    for (int j = 0; j < CH; ++j) {
        int idx = base + j;
        if (idx < NN) {
            rowptrD[idx] = acc;
            cursorD[idx] = acc;
            acc += histD[idx];
        }
    }
    if (tid == 0) rowptrD[NN] = EE;
}

// rewrites sortedR[i].w = dst-sorted position (dummies keep -1);
// relD[dstpos] = relation (u16)
__global__ void k_scatterD(int4* sortedR, int* cursorD, u16* relD) {
    int i = blockIdx.x * blockDim.x + threadIdx.x;
    if (i >= E2) return;
    int4 rec = sortedR[i];
    if (rec.w < 0) return;
    int pos = atomicAdd(&cursorD[rec.y], 1);
    ((int*)(sortedR + i))[3] = pos;
    relD[pos] = (u16)rec.z;
}

// ---------------- weight folding ----------------
__global__ void k_w1(const float* att1, const float* basis1, float* w1) {
    int idx = blockIdx.x * blockDim.x + threadIdx.x;
    if (idx >= RR * 2560) return;
    int r = idx / 2560, co = idx - r * 2560;
    float acc = 0.f;
    for (int b = 0; b < 35; ++b) acc += att1[r * 35 + b] * basis1[b * 2560 + co];
    w1[idx] = acc;
}

__global__ void k_wqk1(const float* w1, const float* q1, const float* k1,
                       float* wq1, float* wk1) {
    int idx = blockIdx.x * blockDim.x + threadIdx.x;
    if (idx >= RR * 64 * 4) return;
    int t = idx & 3, c = (idx >> 2) & 63, r = idx >> 8;
    const float* wrow = w1 + (size_t)r * 2560 + c * 40;
    float aq = 0.f, ak = 0.f;
    for (int o = 0; o < 40; ++o) {
        float w = wrow[o];
        aq += w * q1[o * 4 + t];
        ak += w * k1[o * 4 + t];
    }
    wq1[idx] = aq; wk1[idx] = ak;
}

__global__ void k_wqk2(const float* w2, const float* q2, const float* k2,
                       float* wq2, float* wk2) {
    int idx = blockIdx.x * blockDim.x + threadIdx.x;
    if (idx >= RR * 80 * 2) return;
    int t = idx & 1, bc = (idx >> 1) % 80, r = idx / 160;
    int b = bc / 40, c = bc % 40;
    const float* wbase = w2 + (size_t)((r * 2 + b) * 40 + c) * 32;
    float aq = 0.f, ak = 0.f;
    for (int d = 0; d < 32; ++d) {
        float w = wbase[d];
        aq += w * q2[(b * 32 + d) * 2 + t];
        ak += w * k2[(b * 32 + d) * 2 + t];
    }
    wq2[idx] = aq; wk2[idx] = ak;
}

__global__ void k_we(const float* lew, const float* e2, float* we) {
    int idx = threadIdx.x;
    if (idx >= 32) return;
    int i = idx >> 1, t = idx & 1;
    float acc = 0.f;
    for (int j = 0; j < 64; ++j) acc += lew[i * 64 + j] * e2[j * 2 + t];
    we[idx] = acc;
}

// aeS[posS[e]][2] = edge_attr[e] @ we  — coalesced read, scattered 8B write
__global__ __launch_bounds__(256) void k_ae(const float* ea, const float* weg,
                                            const int* posS, float* aeS) {
    __shared__ float wes[32];
    if (threadIdx.x < 32) wes[threadIdx.x] = weg[threadIdx.x];
    __syncthreads();
    int e = blockIdx.x * 256 + threadIdx.x;
    if (e >= EE) return;
    const float4* ep = (const float4*)(ea + (size_t)e * 16);
    float a0 = 0.f, a1 = 0.f;
#pragma unroll
    for (int cc = 0; cc < 4; ++cc) {
        float4 v = ep[cc];
        const float* vv = (const float*)&v;
#pragma unroll
        for (int j = 0; j < 4; ++j) {
            int ii = cc * 4 + j;
            a0 = fmaf(vv[j], wes[ii * 2 + 0], a0);
            a1 = fmaf(vv[j], wes[ii * 2 + 1], a1);
        }
    }
    float2 av; av.x = a0; av.y = a1;
    *(float2*)(aeS + (size_t)posS[e] * 2) = av;
}

// f16 transposed+padded weights: w1hT[r][o(48)][k(64)]
__global__ void k_w1hT(const float* w1, f16* w1hT) {
    int idx = blockIdx.x * blockDim.x + threadIdx.x;
    if (idx >= RR * 48 * 64) return;
    int k = idx & 63, o = (idx >> 6) % 48, r = idx / (48 * 64);
    float v = (o < 40) ? w1[(size_t)r * 2560 + k * 40 + o] : 0.f;
    w1hT[idx] = (f16)v;
}

// w2hT[r][b][d(32)][c(64)]  (c = K, padded 40->64 with ZEROS — enables
// unpadded h1h B-fragment reads: garbage at K>=40 multiplies zero)
__global__ void k_w2hT(const float* w2, f16* w2hT) {
    int idx = blockIdx.x * blockDim.x + threadIdx.x;
    if (idx >= RR * 2 * 32 * 64) return;
    int c = idx & 63, d = (idx >> 6) & 31, b = (idx >> 11) & 1, r = idx >> 12;
    float v = (c < 40) ? w2[((((size_t)r * 2 + b) * 40) + c) * 32 + d] : 0.f;
    w2hT[idx] = (f16)v;
}

// hh = f16(x @ lin1_w) — single buffer for logits AND MFMA B-operand
__global__ void k_h(const float* x, const float* lin1_w, f16* hh) {
    __shared__ float xs[INF_];
    int n = blockIdx.x, t = threadIdx.x;
    xs[t]      = x[(size_t)n * INF_ + t];
    xs[t + 64] = x[(size_t)n * INF_ + t + 64];
    __syncthreads();
    float acc = 0.f;
    for (int i = 0; i < INF_; ++i) acc += xs[i] * lin1_w[i * HID + t];
    hh[(size_t)n * HID + t] = (f16)acc;
}

// ---------------- conv1 fused: logits + MFMA transform ----------------------
// 64 edges/block (rel-uniform by segment padding). Per wave: 16 edges,
// lane = (edge row16, k-group g). hh[s] fragments feed BOTH kj and MFMA-B.
__global__ __launch_bounds__(256) void k_c1(const int4* sortedR, const f16* hh,
                                            const f16* w1hT,
                                            const float* wq1g, const float* wk1g,
                                            float* alpha1s, f16* outj1h) {
    __shared__ float qs[256], ks[256];
    int base = blockIdx.x * 64;
    int r = sortedR[base].z;
    qs[threadIdx.x] = wq1g[(size_t)r * 256 + threadIdx.x];
    ks[threadIdx.x] = wk1g[(size_t)r * 256 + threadIdx.x];
    __syncthreads();
    int wid = threadIdx.x >> 6, l = threadIdx.x & 63;
    int e0 = base + wid * 16;
    int row16 = l & 15, g = l >> 4;
    f16x8 a[3][2];
#pragma unroll
    for (int mt = 0; mt < 3; ++mt)
#pragma unroll
        for (int kk = 0; kk < 2; ++kk)
            a[mt][kk] = *(const f16x8*)(w1hT + ((size_t)r * 48 + mt * 16 + row16) * 64 + kk * 32 + g * 8);
    int4 er = sortedR[e0 + row16];
    int s = er.x, d = er.y, pd = er.w;
    f16x8 b0 = *(const f16x8*)(hh + (size_t)s * 64 + g * 8);
    f16x8 b1 = *(const f16x8*)(hh + (size_t)s * 64 + 32 + g * 8);
    f16x8 d0 = *(const f16x8*)(hh + (size_t)d * 64 + g * 8);
    f16x8 d1 = *(const f16x8*)(hh + (size_t)d * 64 + 32 + g * 8);
    // logit partials over this lane's 16 positions
    float qi[4] = {0.f, 0.f, 0.f, 0.f}, kj[4] = {0.f, 0.f, 0.f, 0.f};
#pragma unroll
    for (int j = 0; j < 8; ++j) {
        int p0 = g * 8 + j, p1 = 32 + g * 8 + j;
        float dv0 = (float)d0[j], dv1 = (float)d1[j];
        float bv0 = (float)b0[j], bv1 = (float)b1[j];
#pragma unroll
        for (int t = 0; t < 4; ++t) {
            qi[t] = fmaf(dv0, qs[p0 * 4 + t], fmaf(dv1, qs[p1 * 4 + t], qi[t]));
            kj[t] = fmaf(bv0, ks[p0 * 4 + t], fmaf(bv1, ks[p1 * 4 + t], kj[t]));
        }
    }
#pragma unroll
    for (int t = 0; t < 4; ++t) {
        qi[t] += __shfl_xor(qi[t], 16); qi[t] += __shfl_xor(qi[t], 32);
        kj[t] += __shfl_xor(kj[t], 16); kj[t] += __shfl_xor(kj[t], 32);
    }
    f32x4 acc[3];
#pragma unroll
    for (int mt = 0; mt < 3; ++mt) acc[mt] = (f32x4){0.f, 0.f, 0.f, 0.f};
#pragma unroll
    for (int mt = 0; mt < 3; ++mt) {
        acc[mt] = __builtin_amdgcn_mfma_f32_16x16x32_f16(a[mt][0], b0, acc[mt], 0, 0, 0);
        acc[mt] = __builtin_amdgcn_mfma_f32_16x16x32_f16(a[mt][1], b1, acc[mt], 0, 0, 0);
    }
    if (pd < 0) return;   // dummy pad edge (after all collective ops)
    if (l < 16) {
        float4 av;
        av.x = qi[0] * kj[0]; av.y = qi[1] * kj[1];
        av.z = qi[2] * kj[2]; av.w = qi[3] * kj[3];
        *(float4*)(alpha1s + (size_t)pd * 4) = av;
    }
    f16* orow = outj1h + (size_t)pd * 40;
#pragma unroll
    for (int mt = 0; mt < 3; ++mt) {
        int col = mt * 16 + g * 4;
        if (col < 40) {
            f16x4 v;
            v[0] = (f16)acc[mt][0]; v[1] = (f16)acc[mt][1];
            v[2] = (f16)acc[mt][2]; v[3] = (f16)acc[mt][3];
            *(f16x4*)(orow + col) = v;
        }
    }
}

// ---------------- conv1 aggregate + wave-local segment softmax ----------------
__global__ __launch_bounds__(256) void k_aggr1(const u16* relD, const int* rowptrD,
                                               const f16* outj1h, const float* alpha1s,
                                               const float* wmod, const float* bias1,
                                               f16* h1h) {
    __shared__ unsigned smax[4][RR * 5];
    __shared__ float    ssum[4][RR * 5];
    int wid = threadIdx.x >> 6;
    int lane = threadIdx.x & 63;
    int w = blockIdx.x * 4 + wid;       // grid = NN/4 exactly (NN % 4 == 0)
    int beg = rowptrD[w], end = rowptrD[w + 1];
    unsigned* mx = smax[wid];
    float*    sm = ssum[wid];
    for (int j = beg + lane; j < end; j += 64) {
        int rb = relD[j] * 5;
        mx[rb + 0] = ORD_NEGINF; mx[rb + 1] = ORD_NEGINF;
        mx[rb + 2] = ORD_NEGINF; mx[rb + 3] = ORD_NEGINF;
        sm[rb + 0] = 0.f; sm[rb + 1] = 0.f; sm[rb + 2] = 0.f; sm[rb + 3] = 0.f;
    }
    __syncthreads();
    for (int j = beg + lane; j < end; j += 64) {
        float4 a = *(const float4*)(alpha1s + (size_t)j * 4);
        int rb = relD[j] * 5;
        atomicMax(&mx[rb + 0], f2ord(a.x));
        atomicMax(&mx[rb + 1], f2ord(a.y));
        atomicMax(&mx[rb + 2], f2ord(a.z));
        atomicMax(&mx[rb + 3], f2ord(a.w));
    }
    __syncthreads();
    for (int j = beg + lane; j < end; j += 64) {
        float4 a = *(const float4*)(alpha1s + (size_t)j * 4);
        int rb = relD[j] * 5;
        atomicAdd(&sm[rb + 0], __expf(a.x - ord2f(mx[rb + 0])));
        atomicAdd(&sm[rb + 1], __expf(a.y - ord2f(mx[rb + 1])));
        atomicAdd(&sm[rb + 2], __expf(a.z - ord2f(mx[rb + 2])));
        atomicAdd(&sm[rb + 3], __expf(a.w - ord2f(mx[rb + 3])));
    }
    __syncthreads();
    for (int t = lane; t < RR * 5; t += 64) sm[t] = 1.f / (sm[t] + EPS);
    __syncthreads();
    int hh2 = lane >= 20 ? 1 : 0;
    int oo = lane - hh2 * 20;
    float acc0 = 0.f, acc1 = 0.f, accw = 0.f;
    if (lane < 40) {
        for (int j = beg; j < end; ++j) {
            int rb = relD[j] * 5 + hh2 * 2;
            float v = (float)outj1h[(size_t)j * 40 + lane];
            float2 a = *(const float2*)(alpha1s + (size_t)j * 4 + hh2 * 2);
            float e0 = __expf(a.x - ord2f(mx[rb]));
            float e1 = __expf(a.y - ord2f(mx[rb + 1]));
            acc0 = fmaf(v, e0 * sm[rb], acc0);
            acc1 = fmaf(v, e1 * sm[rb + 1], acc1);
            accw += v;
        }
        float wm = wmod[oo];
        int b0 = hh2 * 40 + oo;
        float o0 = fmaxf(acc0 + wm * accw + bias1[b0], 0.f);
        float o1 = fmaxf(acc1 + wm * accw + bias1[b0 + 20], 0.f);
        h1h[(size_t)w * 80 + b0]      = (f16)o0;
        h1h[(size_t)w * 80 + b0 + 20] = (f16)o1;
    }
}

// ---------------- conv2 fused: logits + MFMA transform ----------------------
// B-fragments read UNPADDED h1h[n][80]; K>=40 garbage multiplies zero weights.
__global__ __launch_bounds__(256) void k_c2(const int4* sortedR, const f16* h1h,
                                            const f16* w2hT,
                                            const float* wq2g, const float* wk2g,
                                            const float* aeS,
                                            float* alpha2s, f16* outj2h) {
    __shared__ float qs[160], ks[160];
    int base = blockIdx.x * 64;
    int r = sortedR[base].z;
    if (threadIdx.x < 160) {
        qs[threadIdx.x] = wq2g[(size_t)r * 160 + threadIdx.x];
        ks[threadIdx.x] = wk2g[(size_t)r * 160 + threadIdx.x];
    }
    __syncthreads();
    int wid = threadIdx.x >> 6, l = threadIdx.x & 63;
    int e0 = base + wid * 16;
    int row16 = l & 15, g = l >> 4;
    f16x8 a[2][2][2];   // [b][mt][kk]
#pragma unroll
    for (int b = 0; b < 2; ++b)
#pragma unroll
        for (int mt = 0; mt < 2; ++mt)
#pragma unroll
            for (int kk = 0; kk < 2; ++kk)
                a[b][mt][kk] = *(const f16x8*)(w2hT + ((((size_t)r * 2 + b) * 32) + mt * 16 + row16) * 64 + kk * 32 + g * 8);
    int4 er = sortedR[e0 + row16];
    int s = er.x, d = er.y, pd = er.w;
    f16x8 bb[2][2], dd[2][2];
#pragma unroll
    for (int b = 0; b < 2; ++b)
#pragma unroll
        for (int kk = 0; kk < 2; ++kk) {
            bb[b][kk] = *(const f16x8*)(h1h + (size_t)s * 80 + b * 40 + kk * 32 + g * 8);
            dd[b][kk] = *(const f16x8*)(h1h + (size_t)d * 80 + b * 40 + kk * 32 + g * 8);
        }
    // logit partials (positions p = b*40 + k, k<40 only)
    float a0 = 0.f, a1 = 0.f;
#pragma unroll
    for (int b = 0; b < 2; ++b) {
#pragma unroll
        for (int j = 0; j < 8; ++j) {
            int p = b * 40 + g * 8 + j;          // k = g*8+j <= 31, always valid
            float dv = (float)dd[b][0][j], bv = (float)bb[b][0][j];
            a0 = fmaf(dv, qs[p * 2 + 0], fmaf(bv, ks[p * 2 + 0], a0));
            a1 = fmaf(dv, qs[p * 2 + 1], fmaf(bv, ks[p * 2 + 1], a1));
        }
        if (g == 0) {                            // k = 32..39 handled by g==0
#pragma unroll
            for (int j = 0; j < 8; ++j) {
                int p = b * 40 + 32 + j;
                float dv = (float)dd[b][1][j], bv = (float)bb[b][1][j];
                a0 = fmaf(dv, qs[p * 2 + 0], fmaf(bv, ks[p * 2 + 0], a0));
                a1 = fmaf(dv, qs[p * 2 + 1], fmaf(bv, ks[p * 2 + 1], a1));
            }
        }
    }
    a0 += __shfl_xor(a0, 16); a0 += __shfl_xor(a0, 32);
    a1 += __shfl_xor(a1, 16); a1 += __shfl_xor(a1, 32);
    f32x4 acc[2][2];
#pragma unroll
    for (int b = 0; b < 2; ++b)
#pragma unroll
        for (int mt = 0; mt < 2; ++mt) acc[b][mt] = (f32x4){0.f, 0.f, 0.f, 0.f};
#pragma unroll
    for (int b = 0; b < 2; ++b)
#pragma unroll
        for (int mt = 0; mt < 2; ++mt) {
            acc[b][mt] = __builtin_amdgcn_mfma_f32_16x16x32_f16(a[b][mt][0], bb[b][0], acc[b][mt], 0, 0, 0);
            acc[b][mt] = __builtin_amdgcn_mfma_f32_16x16x32_f16(a[b][mt][1], bb[b][1], acc[b][mt], 0, 0, 0);
        }
    if (pd < 0) return;   // dummy pad edge (after all collective ops)
    if (l < 16) {
        float2 aev = *(const float2*)(aeS + (size_t)(e0 + row16) * 2);  // linear
        float x0 = a0 + aev.x, x1 = a1 + aev.y;
        x0 = x0 > 0.f ? x0 : 0.2f * x0;
        x1 = x1 > 0.f ? x1 : 0.2f * x1;
        float2 av; av.x = x0; av.y = x1;
        *(float2*)(alpha2s + (size_t)pd * 2) = av;
    }
    f16* orow = outj2h + (size_t)pd * 64;
#pragma unroll
    for (int b = 0; b < 2; ++b)
#pragma unroll
        for (int mt = 0; mt < 2; ++mt) {
            f16x4 v;
            v[0] = (f16)acc[b][mt][0]; v[1] = (f16)acc[b][mt][1];
            v[2] = (f16)acc[b][mt][2]; v[3] = (f16)acc[b][mt][3];
            *(f16x4*)(orow + b * 32 + mt * 16 + g * 4) = v;
        }
}

// ---------------- conv2 aggregate + wave-local softmax (per-dst segments) ----
__global__ __launch_bounds__(256) void k_aggr2(const int* rowptrD, const f16* outj2h,
                                               const float* alpha2s, float* h2) {
    int w = blockIdx.x * 4 + (threadIdx.x >> 6);
    int lane = threadIdx.x & 63;
    if (w >= NN) return;
    int beg = rowptrD[w], end = rowptrD[w + 1];
    float m0 = -INFINITY, m1 = -INFINITY;
    for (int j = beg + lane; j < end; j += 64) {
        float2 a = *(const float2*)(alpha2s + (size_t)j * 2);
        m0 = fmaxf(m0, a.x); m1 = fmaxf(m1, a.y);
    }
#pragma unroll
    for (int off = 32; off; off >>= 1) {
        m0 = fmaxf(m0, __shfl_xor(m0, off));
        m1 = fmaxf(m1, __shfl_xor(m1, off));
    }
    float s0 = 0.f, s1 = 0.f;
    for (int j = beg + lane; j < end; j += 64) {
        float2 a = *(const float2*)(alpha2s + (size_t)j * 2);
        s0 += __expf(a.x - m0); s1 += __expf(a.y - m1);
    }
#pragma unroll
    for (int off = 32; off; off >>= 1) {
        s0 += __shfl_xor(s0, off);
        s1 += __shfl_xor(s1, off);
    }
    int b = lane >> 5;
    float mb = b ? m1 : m0;
    float rs = 1.f / ((b ? s1 : s0) + EPS);
    float acc = 0.f;
    for (int j = beg; j < end; ++j) {
        float v = (float)outj2h[(size_t)j * 64 + lane];
        float a = alpha2s[(size_t)j * 2 + b];
        acc = fmaf(v, __expf(a - mb) * rs, acc);
    }
    h2[(size_t)w * 64 + lane] = acc;
}

__global__ void k_out(const float* h2, const float* lin2_w, const float* lin2_b,
                      float* out) {
    int n = blockIdx.x * blockDim.x + threadIdx.x;
    if (n >= NN) return;
    float o[4] = {lin2_b[0], lin2_b[1], lin2_b[2], lin2_b[3]};
    const float* hr = h2 + (size_t)n * 64;
    for (int c = 0; c < 64; ++c) {
        float hv = hr[c];
#pragma unroll
        for (int t = 0; t < 4; ++t) o[t] = fmaf(hv, lin2_w[c * 4 + t], o[t]);
    }
    float m = fmaxf(fmaxf(o[0], o[1]), fmaxf(o[2], o[3]));
    float s = __expf(o[0] - m) + __expf(o[1] - m) + __expf(o[2] - m) + __expf(o[3] - m);
    float lse = m + logf(s);
#pragma unroll
    for (int t = 0; t < 4; ++t) out[(size_t)n * 4 + t] = o[t] - lse;
}

extern "C" void kernel_launch(void* const* d_in, const int* in_sizes, int n_in,
                              void* d_out, int out_size, void* d_ws, size_t ws_size,
                              hipStream_t stream) {
    const float* x        = (const float*)d_in[0];
    const int*   eidx     = (const int*)d_in[1];
    const int*   etype    = (const int*)d_in[2];
    const float* eattr    = (const float*)d_in[3];
    const float* lin1_w   = (const float*)d_in[4];
    const float* att1     = (const float*)d_in[5];
    const float* basis1   = (const float*)d_in[6];
    const float* q1       = (const float*)d_in[7];
    const float* k1       = (const float*)d_in[8];
    const float* wmod1    = (const float*)d_in[9];
    const float* bias1    = (const float*)d_in[10];
    const float* w2       = (const float*)d_in[11];
    const float* q2       = (const float*)d_in[12];
    const float* k2       = (const float*)d_in[13];
    const float* lew      = (const float*)d_in[14];
    const float* e2i      = (const float*)d_in[15];
    const float* lin2_w   = (const float*)d_in[16];
    const float* lin2_b   = (const float*)d_in[17];

    const int* src = eidx;
    const int* dst = eidx + EE;

    // ---------------- workspace layout (f32 units) ----------------
    float* W = (float*)d_ws;
    float* w1      = W;   W += 230400;
    float* wq1     = W;   W += 23040;
    float* wk1     = W;   W += 23040;
    float* wq2     = W;   W += 14400;
    float* wk2     = W;   W += 14400;
    float* we      = W;   W += 32;
    float* h2      = W;   W += (size_t)NN * 64;
    float* aeS     = W;   W += (size_t)E2 * 2;
    f16*   hh      = (f16*)W;   W += (size_t)NN * 64 / 2;        // N*64 f16 (logits+MFMA)
    f16*   h1h     = (f16*)W;   W += (size_t)NN * 80 / 2 + 32;   // N*80 f16 + 64-elem pad
    f16*   w1hT    = (f16*)W;   W += (size_t)RR * 48 * 64 / 2;
    f16*   w2hT    = (f16*)W;   W += (size_t)RR * 2 * 32 * 64 / 2;
    // union region: conv1 {outj1h[EE*40 f16], alpha1s[EE*4 f32]} / conv2 {outj2h[EE*64 f16]}
    float* uni     = W;   W += (size_t)EE * 20 + (size_t)EE * 4;  // 24 f32-units/edge
    f16*   outj1h  = (f16*)uni;
    float* alpha1s = uni + (size_t)EE * 20;
    f16*   outj2h  = (f16*)uni;
    W += (size_t)EE * 8;                   // extend union to EE*32 f32 for outj2h
    float* alpha2s = W;   W += (size_t)EE * 2;
    int4*  sortedR = (int4*)W;
    int*   I = (int*)W;   I += (size_t)E2 * 4;
    u16*   relD    = (u16*)I;   I += (size_t)E2 / 2;
    int*   posS    = I;   I += EE;
    int*   rowptrD = I;   I += NN + 1;
    int*   cursorD = I;   I += NN;
    int*   histD   = I;   I += NN;    // zeroed block starts here
    int*   hist    = I;   I += 128;
    int*   cursor  = I;   I += 128;

    // ---------------- init ----------------
    hipMemsetAsync(histD, 0, (size_t)(NN + 256) * 4, stream);
    hipMemsetAsync(h1h + (size_t)NN * 80, 0, 128, stream);  // zero K-pad tail
    k_fillrec<<<E2 / 256, 256, 0, stream>>>(sortedR, E2);

    // sorts
    k_hist<<<EE / 256, 256, 0, stream>>>(etype, hist);
    k_scanPad<<<1, 64, 0, stream>>>(hist, cursor);
    k_scatter<<<EE / 256, 256, 0, stream>>>(src, dst, etype, cursor, sortedR, posS);
    k_histD<<<EE / 256, 256, 0, stream>>>(dst, histD);
    k_scanD<<<1, 256, 0, stream>>>(histD, rowptrD, cursorD);
    k_scatterD<<<E2 / 256, 256, 0, stream>>>(sortedR, cursorD, relD);

    // folded weights + f16 prep + dense input layer + edge-attr logits
    k_w1<<<(RR * 2560 + 255) / 256, 256, 0, stream>>>(att1, basis1, w1);
    k_wqk1<<<(RR * 256 + 255) / 256, 256, 0, stream>>>(w1, q1, k1, wq1, wk1);
    k_wqk2<<<(RR * 160 + 255) / 256, 256, 0, stream>>>(w2, q2, k2, wq2, wk2);
    k_we<<<1, 32, 0, stream>>>(lew, e2i, we);
    k_ae<<<EE / 256, 256, 0, stream>>>(eattr, we, posS, aeS);
    k_w1hT<<<(RR * 48 * 64) / 256, 256, 0, stream>>>(w1, w1hT);
    k_w2hT<<<(RR * 2 * 32 * 64) / 256, 256, 0, stream>>>(w2, w2hT);
    k_h<<<NN, 64, 0, stream>>>(x, lin1_w, hh);

    // conv1 (fused logits + transform)
    k_c1<<<E2 / 64, 256, 0, stream>>>(sortedR, hh, w1hT, wq1, wk1, alpha1s, outj1h);
    k_aggr1<<<NN / 4, 256, 0, stream>>>(relD, rowptrD, outj1h, alpha1s,
                                        wmod1, bias1, h1h);

    // conv2 (fused; outj2h aliases dead conv1 buffers)
    k_c2<<<E2 / 64, 256, 0, stream>>>(sortedR, h1h, w2hT, wq2, wk2, aeS,
                                      alpha2s, outj2h);
    k_aggr2<<<(NN + 3) / 4, 256, 0, stream>>>(rowptrD, outj2h, alpha2s, h2);

    k_out<<<(NN + 255) / 256, 256, 0, stream>>>(h2, lin2_w, lin2_b, (float*)d_out);
}